// Round 1
// baseline (4716.396 us; speedup 1.0000x reference)
//
#include <hip/hip_runtime.h>
#include <cmath>

#define N_TOK 196
#define NPX   (196 * 196)   // 38416
#define CDIM  256

// ---------------------------------------------------------------------------
// Generic fp32 GEMM: C = A@B (+bias), batched via grid.z with element strides.
// block 256 (16x16), tile 64x64, BK=16, 4x4 micro-tile.
// ---------------------------------------------------------------------------
__global__ __launch_bounds__(256) void gemm_f32(
    const float* __restrict__ A, const float* __restrict__ B, float* __restrict__ C,
    int M, int N, int K, int lda, int ldb, int ldc,
    const float* __restrict__ bias,
    long long sA, long long sB, long long sC)
{
    A += (long long)blockIdx.z * sA;
    B += (long long)blockIdx.z * sB;
    C += (long long)blockIdx.z * sC;
    __shared__ float As[16][68];
    __shared__ float Bs[16][68];
    int tid = threadIdx.x;
    int tx = tid & 15, ty = tid >> 4;
    int m0 = blockIdx.y * 64, n0 = blockIdx.x * 64;
    float acc[4][4] = {};
    for (int k0 = 0; k0 < K; k0 += 16) {
        __syncthreads();
        for (int e = tid; e < 1024; e += 256) {
            int m = e >> 4, kk = e & 15;
            int gm = m0 + m, gk = k0 + kk;
            As[kk][m] = (gm < M && gk < K) ? A[(long long)gm * lda + gk] : 0.f;
        }
        for (int e = tid; e < 1024; e += 256) {
            int kk = e >> 6, n = e & 63;
            int gk = k0 + kk, gn = n0 + n;
            Bs[kk][n] = (gk < K && gn < N) ? B[(long long)gk * ldb + gn] : 0.f;
        }
        __syncthreads();
        #pragma unroll
        for (int kk = 0; kk < 16; ++kk) {
            float4 av = *(const float4*)&As[kk][ty * 4];
            float4 bv = *(const float4*)&Bs[kk][tx * 4];
            float a[4] = {av.x, av.y, av.z, av.w};
            float b[4] = {bv.x, bv.y, bv.z, bv.w};
            #pragma unroll
            for (int u = 0; u < 4; ++u)
                #pragma unroll
                for (int v = 0; v < 4; ++v) acc[u][v] += a[u] * b[v];
        }
    }
    #pragma unroll
    for (int u = 0; u < 4; ++u) {
        int gm = m0 + ty * 4 + u;
        if (gm >= M) continue;
        #pragma unroll
        for (int v = 0; v < 4; ++v) {
            int gn = n0 + tx * 4 + v;
            if (gn >= N) continue;
            float val = acc[u][v];
            if (bias) val += bias[gn];
            C[(long long)gm * ldc + gn] = val;
        }
    }
}

// ---------------------------------------------------------------------------
// Branch 0: fused pair -> 1x1 conv stack (256->128->64->1, relu each) -> X0.
// Tile: 8x8 pixels. pair[b,i,j,c] = sub[b,i,c]*sub[b,j,c] computed on the fly.
// LDS: union region U (phase1: Si/Sj/Ws, phase2: W2s+H2) + H1. Total ~58 KB.
// ---------------------------------------------------------------------------
__global__ __launch_bounds__(256, 2) void branch0_fused(
    const float* __restrict__ sub,
    const float* __restrict__ w01, const float* __restrict__ b01,
    const float* __restrict__ w02, const float* __restrict__ b02,
    const float* __restrict__ w03, const float* __restrict__ b03,
    float* __restrict__ X0)
{
    __shared__ float U[6208];
    __shared__ float H1[64][129];   // h1: 64 px x 128, pad 129 (odd stride)
    __shared__ float W3s[64];
    float* Si  = U;            // phase1: [8][258]
    float* Sj  = U + 2064;     // phase1: [8][258]
    float* Ws  = U + 4128;     // phase1: w01 chunk [16][128]
    float* W2s = U;            // phase2: w02 chunk [32][64]
    float* H2  = U + 2048;     // phase2/3: [64][65]

    int b = blockIdx.z;
    int i0 = blockIdx.y * 8, j0 = blockIdx.x * 8;
    const float* subB = sub + (long long)b * N_TOK * CDIM;
    int tid = threadIdx.x;

    for (int e = tid; e < 8 * 256; e += 256) {
        int r = e >> 8, c = e & 255;
        int gi = i0 + r;
        Si[r * 258 + c] = (gi < N_TOK) ? subB[gi * CDIM + c] : 0.f;
        int gj = j0 + r;
        Sj[r * 258 + c] = (gj < N_TOK) ? subB[gj * CDIM + c] : 0.f;
    }
    if (tid < 64) W3s[tid] = w03[tid];

    int pxg = tid & 31;     // handles px pxg and pxg+32
    int dg  = tid >> 5;     // 8 groups of 16 outputs
    int d0  = dg * 16;
    int ti  = pxg >> 3, tj = pxg & 7;

    float4 acc[2][4];
    #pragma unroll
    for (int p = 0; p < 2; ++p)
        #pragma unroll
        for (int q = 0; q < 4; ++q) acc[p][q] = make_float4(0.f, 0.f, 0.f, 0.f);

    const float* arow0 = Si + ti * 258;
    const float* arow1 = Si + (ti + 4) * 258;
    const float* brow  = Sj + tj * 258;

    // ---- layer 1: pair @ w01 ----
    for (int c0 = 0; c0 < 256; c0 += 16) {
        __syncthreads();
        for (int e = tid; e < 2048; e += 256) {
            int cc = e >> 7, dd = e & 127;
            Ws[cc * 128 + dd] = w01[(c0 + cc) * 128 + dd];
        }
        __syncthreads();
        #pragma unroll 4
        for (int cc = 0; cc < 16; ++cc) {
            int c = c0 + cc;
            float bj = brow[c];
            float pA = arow0[c] * bj;
            float pB = arow1[c] * bj;
            const float4* wr = (const float4*)(Ws + cc * 128 + d0);
            #pragma unroll
            for (int q = 0; q < 4; ++q) {
                float4 w4 = wr[q];
                acc[0][q].x += pA * w4.x; acc[0][q].y += pA * w4.y;
                acc[0][q].z += pA * w4.z; acc[0][q].w += pA * w4.w;
                acc[1][q].x += pB * w4.x; acc[1][q].y += pB * w4.y;
                acc[1][q].z += pB * w4.z; acc[1][q].w += pB * w4.w;
            }
        }
    }
    {   // write H1 with bias + relu
        const float4* bb4 = (const float4*)(b01 + d0);
        float4 bv[4] = {bb4[0], bb4[1], bb4[2], bb4[3]};
        #pragma unroll
        for (int p = 0; p < 2; ++p) {
            int px = pxg + 32 * p;
            float* h = &H1[px][d0];
            #pragma unroll
            for (int q = 0; q < 4; ++q) {
                h[q * 4 + 0] = fmaxf(acc[p][q].x + bv[q].x, 0.f);
                h[q * 4 + 1] = fmaxf(acc[p][q].y + bv[q].y, 0.f);
                h[q * 4 + 2] = fmaxf(acc[p][q].z + bv[q].z, 0.f);
                h[q * 4 + 3] = fmaxf(acc[p][q].w + bv[q].w, 0.f);
            }
        }
    }
    // ---- layer 2: h1 @ w02 ----
    int e0 = dg * 8;
    float4 acc2[2][2];
    #pragma unroll
    for (int p = 0; p < 2; ++p)
        #pragma unroll
        for (int q = 0; q < 2; ++q) acc2[p][q] = make_float4(0.f, 0.f, 0.f, 0.f);

    for (int c0 = 0; c0 < 128; c0 += 32) {
        __syncthreads();   // first iter: H1 complete + Si/Sj dead; later: W2s reuse
        for (int e = tid; e < 2048; e += 256) {
            int cc = e >> 6, ee = e & 63;
            W2s[cc * 64 + ee] = w02[(c0 + cc) * 64 + ee];
        }
        __syncthreads();
        #pragma unroll 4
        for (int cc = 0; cc < 32; ++cc) {
            int c = c0 + cc;
            float hA = H1[pxg][c];
            float hB = H1[pxg + 32][c];
            const float4* wr = (const float4*)(W2s + cc * 64 + e0);
            float4 w0 = wr[0], w1 = wr[1];
            acc2[0][0].x += hA * w0.x; acc2[0][0].y += hA * w0.y;
            acc2[0][0].z += hA * w0.z; acc2[0][0].w += hA * w0.w;
            acc2[0][1].x += hA * w1.x; acc2[0][1].y += hA * w1.y;
            acc2[0][1].z += hA * w1.z; acc2[0][1].w += hA * w1.w;
            acc2[1][0].x += hB * w0.x; acc2[1][0].y += hB * w0.y;
            acc2[1][0].z += hB * w0.z; acc2[1][0].w += hB * w0.w;
            acc2[1][1].x += hB * w1.x; acc2[1][1].y += hB * w1.y;
            acc2[1][1].z += hB * w1.z; acc2[1][1].w += hB * w1.w;
        }
    }
    {   // write H2 = relu(acc2 + b02)  (H2 region does not alias W2s)
        #pragma unroll
        for (int p = 0; p < 2; ++p) {
            int px = pxg + 32 * p;
            float* h = H2 + px * 65 + e0;
            h[0] = fmaxf(acc2[p][0].x + b02[e0 + 0], 0.f);
            h[1] = fmaxf(acc2[p][0].y + b02[e0 + 1], 0.f);
            h[2] = fmaxf(acc2[p][0].z + b02[e0 + 2], 0.f);
            h[3] = fmaxf(acc2[p][0].w + b02[e0 + 3], 0.f);
            h[4] = fmaxf(acc2[p][1].x + b02[e0 + 4], 0.f);
            h[5] = fmaxf(acc2[p][1].y + b02[e0 + 5], 0.f);
            h[6] = fmaxf(acc2[p][1].z + b02[e0 + 6], 0.f);
            h[7] = fmaxf(acc2[p][1].w + b02[e0 + 7], 0.f);
        }
    }
    __syncthreads();
    // ---- layer 3: h2 @ w03 -> scalar ----
    if (tid < 64) {
        float s = b03[0];
        const float* h = H2 + tid * 65;
        #pragma unroll 8
        for (int c = 0; c < 64; ++c) s += h[c] * W3s[c];
        int i = i0 + (tid >> 3), j = j0 + (tid & 7);
        if (i < N_TOK && j < N_TOK)
            X0[(long long)b * NPX + i * N_TOK + j] = fmaxf(s, 0.f);
    }
}

// ---------------------------------------------------------------------------
// Conv1 fused with pair: Y1[b,i,j,d] = relu(b1 + sum_{di,dj,c} w1*sub_i*sub_j)
// Output tile 16(i) x 32(j) x 32(d); thread: 2 px x 32 d. LDS ~58 KB.
// grid: (7 jt, 13 it, 4*nb) ; z = bb*4 + dchunk
// ---------------------------------------------------------------------------
__global__ __launch_bounds__(256, 2) void conv1_fused(
    const float* __restrict__ sub,   // full [8][196][256]
    const float* __restrict__ w1,    // [9][256][128]
    const float* __restrict__ b1,    // [128]
    float* __restrict__ Y1,          // [nb][196][196][128]
    int batch0)
{
    __shared__ float Si[18 * 261];
    __shared__ float Sj[34 * 261];
    __shared__ float Wc[32 * 32];
    int bz = blockIdx.z;
    int bb = bz >> 2, dc = bz & 3;
    int d0 = dc * 32;
    const float* subB = sub + (long long)(batch0 + bb) * N_TOK * CDIM;
    float* Yb = Y1 + (long long)bb * NPX * 128;
    int i0 = blockIdx.y * 16, j0 = blockIdx.x * 32;
    int tid = threadIdx.x;

    for (int e = tid; e < 18 * 256; e += 256) {
        int r = e >> 8, c = e & 255;
        int gi = i0 - 1 + r;
        Si[r * 261 + c] = (gi >= 0 && gi < N_TOK) ? subB[gi * CDIM + c] : 0.f;
    }
    for (int e = tid; e < 34 * 256; e += 256) {
        int r = e >> 8, c = e & 255;
        int gj = j0 - 1 + r;
        Sj[r * 261 + c] = (gj >= 0 && gj < N_TOK) ? subB[gj * CDIM + c] : 0.f;
    }

    int ti  = tid >> 4;           // 0..15
    int tjg = (tid & 15) * 2;     // 0..30 (2 px per thread)

    float4 acc[2][8];
    #pragma unroll
    for (int p = 0; p < 2; ++p)
        #pragma unroll
        for (int q = 0; q < 8; ++q) acc[p][q] = make_float4(0.f, 0.f, 0.f, 0.f);

    for (int tap = 0; tap < 9; ++tap) {
        int di = tap / 3, dj = tap - di * 3;
        const float* arow  = Si + (ti + di) * 261;
        const float* brow0 = Sj + (tjg + dj) * 261;
        const float* brow1 = brow0 + 261;
        for (int c0 = 0; c0 < 256; c0 += 32) {
            __syncthreads();
            for (int e = tid; e < 1024; e += 256) {
                int cc = e >> 5, dd = e & 31;
                Wc[cc * 32 + dd] = w1[(long long)(tap * 256 + c0 + cc) * 128 + d0 + dd];
            }
            __syncthreads();
            #pragma unroll 4
            for (int cc = 0; cc < 32; ++cc) {
                int c = c0 + cc;
                float a  = arow[c];
                float p0 = a * brow0[c];
                float p1 = a * brow1[c];
                const float4* wr = (const float4*)(Wc + cc * 32);
                #pragma unroll
                for (int q = 0; q < 8; ++q) {
                    float4 w4 = wr[q];
                    acc[0][q].x += p0 * w4.x; acc[0][q].y += p0 * w4.y;
                    acc[0][q].z += p0 * w4.z; acc[0][q].w += p0 * w4.w;
                    acc[1][q].x += p1 * w4.x; acc[1][q].y += p1 * w4.y;
                    acc[1][q].z += p1 * w4.z; acc[1][q].w += p1 * w4.w;
                }
            }
        }
    }
    int i = i0 + ti;
    if (i < N_TOK) {
        const float4* bb4 = (const float4*)(b1 + d0);
        float4 bv[8];
        #pragma unroll
        for (int q = 0; q < 8; ++q) bv[q] = bb4[q];
        #pragma unroll
        for (int p = 0; p < 2; ++p) {
            int j = j0 + tjg + p;
            if (j < N_TOK) {
                float4* dst = (float4*)(Yb + ((long long)i * N_TOK + j) * 128 + d0);
                #pragma unroll
                for (int q = 0; q < 8; ++q) {
                    float4 v;
                    v.x = fmaxf(acc[p][q].x + bv[q].x, 0.f);
                    v.y = fmaxf(acc[p][q].y + bv[q].y, 0.f);
                    v.z = fmaxf(acc[p][q].z + bv[q].z, 0.f);
                    v.w = fmaxf(acc[p][q].w + bv[q].w, 0.f);
                    dst[q] = v;
                }
            }
        }
    }
}

// ---------------------------------------------------------------------------
// Conv2: 3x3, rhs_dilation (1,2), 128->64, relu. NHWC, SAME.
// Tile 16x16 px, all 64 outs; thread: 4 px x 16 e. LDS ~57 KB.
// ---------------------------------------------------------------------------
__global__ __launch_bounds__(256, 2) void conv2_fused(
    const float* __restrict__ Y1, const float* __restrict__ w2,
    const float* __restrict__ b2, float* __restrict__ Y2)
{
    __shared__ float In[32 * 378];   // [cc][r*21+col], r<18, col<20 (pad 21)
    __shared__ float Wc[32 * 64];
    int bb = blockIdx.z;
    const float* Yin = Y1 + (long long)bb * NPX * 128;
    float* Yout = Y2 + (long long)bb * NPX * 64;
    int i0 = blockIdx.y * 16, j0 = blockIdx.x * 16;
    int tid = threadIdx.x;
    int pxg = tid & 63, eg = tid >> 6;
    int e0 = eg * 16;
    int ti = pxg >> 2, tjq = (pxg & 3) * 4;

    float4 acc[4][4];
    #pragma unroll
    for (int p = 0; p < 4; ++p)
        #pragma unroll
        for (int q = 0; q < 4; ++q) acc[p][q] = make_float4(0.f, 0.f, 0.f, 0.f);

    for (int c0 = 0; c0 < 128; c0 += 32) {
        __syncthreads();
        for (int e = tid; e < 18 * 20 * 32; e += 256) {
            int cc = e & 31, pos = e >> 5;
            int r = pos / 20, col = pos - r * 20;
            int gi = i0 - 1 + r, gj = j0 - 2 + col;
            float v = 0.f;
            if (gi >= 0 && gi < N_TOK && gj >= 0 && gj < N_TOK)
                v = Yin[((long long)gi * N_TOK + gj) * 128 + c0 + cc];
            In[cc * 378 + r * 21 + col] = v;
        }
        __syncthreads();
        for (int tap = 0; tap < 9; ++tap) {
            int di = tap / 3, dj2 = (tap - di * 3) * 2;
            __syncthreads();
            for (int e = tid; e < 2048; e += 256) {
                int cc = e >> 6, ee = e & 63;
                Wc[cc * 64 + ee] = w2[(long long)(tap * 128 + c0 + cc) * 64 + ee];
            }
            __syncthreads();
            int rb = (ti + di) * 21 + tjq + dj2;
            #pragma unroll 4
            for (int cc = 0; cc < 32; ++cc) {
                const float* inr = In + cc * 378 + rb;
                float pp[4] = {inr[0], inr[1], inr[2], inr[3]};
                const float4* wr = (const float4*)(Wc + cc * 64 + e0);
                float4 w[4] = {wr[0], wr[1], wr[2], wr[3]};
                #pragma unroll
                for (int p = 0; p < 4; ++p)
                    #pragma unroll
                    for (int q = 0; q < 4; ++q) {
                        acc[p][q].x += pp[p] * w[q].x;
                        acc[p][q].y += pp[p] * w[q].y;
                        acc[p][q].z += pp[p] * w[q].z;
                        acc[p][q].w += pp[p] * w[q].w;
                    }
            }
        }
    }
    int i = i0 + ti;
    if (i < N_TOK) {
        const float4* bb4 = (const float4*)(b2 + e0);
        float4 bv[4] = {bb4[0], bb4[1], bb4[2], bb4[3]};
        #pragma unroll
        for (int p = 0; p < 4; ++p) {
            int j = j0 + tjq + p;
            if (j < N_TOK) {
                float4* dst = (float4*)(Yout + ((long long)i * N_TOK + j) * 64 + e0);
                #pragma unroll
                for (int q = 0; q < 4; ++q) {
                    float4 v;
                    v.x = fmaxf(acc[p][q].x + bv[q].x, 0.f);
                    v.y = fmaxf(acc[p][q].y + bv[q].y, 0.f);
                    v.z = fmaxf(acc[p][q].z + bv[q].z, 0.f);
                    v.w = fmaxf(acc[p][q].w + bv[q].w, 0.f);
                    dst[q] = v;
                }
            }
        }
    }
}

// ---------------------------------------------------------------------------
// Conv3: 3x3, dilation (1,4), 64->1, relu -> X1[b,i,j]
// ---------------------------------------------------------------------------
__global__ __launch_bounds__(256) void conv3_fused(
    const float* __restrict__ Y2, const float* __restrict__ w3,
    const float* __restrict__ b3, float* __restrict__ X1, int batch0)
{
    __shared__ float w[576];
    int bb = blockIdx.y;
    const float* Yin = Y2 + (long long)bb * NPX * 64;
    float* Xout = X1 + (long long)(batch0 + bb) * NPX;
    for (int e = threadIdx.x; e < 576; e += 256) w[e] = w3[e];
    __syncthreads();
    int px = blockIdx.x * 256 + threadIdx.x;
    if (px >= NPX) return;
    int i = px / 196, j = px - i * 196;
    float s = b3[0];
    for (int tap = 0; tap < 9; ++tap) {
        int di = tap / 3 - 1, dj = (tap % 3 - 1) * 4;
        int gi = i + di, gj = j + dj;
        if (gi < 0 || gi >= N_TOK || gj < 0 || gj >= N_TOK) continue;
        const float4* src = (const float4*)(Yin + ((long long)gi * N_TOK + gj) * 64);
        const float4* wt = (const float4*)(w + tap * 64);
        #pragma unroll
        for (int q = 0; q < 16; ++q) {
            float4 a = src[q], b = wt[q];
            s += a.x * b.x + a.y * b.y + a.z * b.z + a.w * b.w;
        }
    }
    Xout[px] = fmaxf(s, 0.f);
}

// ---------------------------------------------------------------------------
// Symmetrize (X + X^T, symmetric so later transpose is a no-op), softmax over
// the 38416 flattened logits, fold the final /2 into the normalization.
// One block (1024 thr) per (b, map). Values held in registers between phases.
// ---------------------------------------------------------------------------
__global__ __launch_bounds__(1024) void symsoftmax(float* __restrict__ X0,
                                                   float* __restrict__ X1)
{
    __shared__ float red[32];
    __shared__ float red2[32];
    float* X = (blockIdx.y ? X1 : X0) + (long long)blockIdx.x * NPX;
    int tid = threadIdx.x;
    float v[38];
    float mx = -3.0e38f;
    #pragma unroll
    for (int p = 0; p < 38; ++p) {
        int e = tid + p * 1024;
        if (e < NPX) {
            int i = e / 196, j = e - i * 196;
            float t = X[e] + X[j * 196 + i];
            v[p] = t;
            mx = fmaxf(mx, t);
        } else v[p] = -3.0e38f;
    }
    #pragma unroll
    for (int off = 32; off > 0; off >>= 1) mx = fmaxf(mx, __shfl_xor(mx, off));
    if ((tid & 63) == 0) red[tid >> 6] = mx;
    __syncthreads();
    if (tid < 64) {
        float m = (tid < 16) ? red[tid] : -3.0e38f;
        #pragma unroll
        for (int off = 8; off > 0; off >>= 1) m = fmaxf(m, __shfl_xor(m, off));
        if (tid == 0) red[0] = m;
    }
    __syncthreads();
    mx = red[0];
    float s = 0.f;
    #pragma unroll
    for (int p = 0; p < 38; ++p) {
        int e = tid + p * 1024;
        float ex = (e < NPX) ? expf(v[p] - mx) : 0.f;
        v[p] = ex;
        s += ex;
    }
    #pragma unroll
    for (int off = 32; off > 0; off >>= 1) s += __shfl_xor(s, off);
    if ((tid & 63) == 0) red2[tid >> 6] = s;
    __syncthreads();
    if (tid < 64) {
        float m = (tid < 16) ? red2[tid] : 0.f;
        #pragma unroll
        for (int off = 8; off > 0; off >>= 1) m += __shfl_xor(m, off);
        if (tid == 0) red2[0] = m;
    }
    __syncthreads();
    float scale = 0.5f / red2[0];   // fold /(2G)
    #pragma unroll
    for (int p = 0; p < 38; ++p) {
        int e = tid + p * 1024;
        if (e < NPX) X[e] = v[p] * scale;
    }
}

__global__ void combine_maps(float* __restrict__ X0, const float* __restrict__ X1, int n)
{
    int e = blockIdx.x * 256 + threadIdx.x;
    if (e < n) X0[e] += X1[e];
}

// ---------------------------------------------------------------------------
extern "C" void kernel_launch(void* const* d_in, const int* in_sizes, int n_in,
                              void* d_out, int out_size, void* d_ws, size_t ws_size,
                              hipStream_t stream)
{
    (void)in_sizes; (void)n_in; (void)out_size;
    const float* x     = (const float*)d_in[0];
    const float* w_prj = (const float*)d_in[1];
    const float* b_prj = (const float*)d_in[2];
    const float* w01   = (const float*)d_in[3];
    const float* b01   = (const float*)d_in[4];
    const float* w02   = (const float*)d_in[5];
    const float* b02   = (const float*)d_in[6];
    const float* w03   = (const float*)d_in[7];
    const float* b03   = (const float*)d_in[8];
    const float* w1    = (const float*)d_in[9];
    const float* b1    = (const float*)d_in[10];
    const float* w2    = (const float*)d_in[11];
    const float* b2    = (const float*)d_in[12];
    const float* w3    = (const float*)d_in[13];
    const float* b3    = (const float*)d_in[14];

    float* ws  = (float*)d_ws;
    float* sub = ws;                 // 8*196*256     = 401408
    float* X0  = ws + 401408;        // 8*38416       = 307328
    float* X1  = X0 + 307328;        // 307328
    float* Y1  = X1 + 307328;        // nb*38416*128
    const size_t base = 1016064u;
    // pick the largest batch group (8/4/2/1) that fits the workspace
    int nb = 1;
    if ((base + 8ull * 7375872ull) * 4ull <= ws_size) nb = 8;
    else if ((base + 4ull * 7375872ull) * 4ull <= ws_size) nb = 4;
    else if ((base + 2ull * 7375872ull) * 4ull <= ws_size) nb = 2;
    float* Y2 = Y1 + (size_t)nb * 4917248u;   // nb*38416*64

    // 1. sub = x @ w_prj + b_prj        [1568,2048]x[2048,256]
    gemm_f32<<<dim3(4, 25, 1), 256, 0, stream>>>(
        x, w_prj, sub, 1568, 256, 2048, 2048, 256, 256, b_prj, 0, 0, 0);

    // 2. branch 0 -> X0 logits
    branch0_fused<<<dim3(25, 25, 8), 256, 0, stream>>>(
        sub, w01, b01, w02, b02, w03, b03, X0);

    // 3. conv branch -> X1 logits (grouped over batches to fit ws)
    for (int g = 0; g < 8; g += nb) {
        conv1_fused<<<dim3(7, 13, nb * 4), 256, 0, stream>>>(sub, w1, b1, Y1, g);
        conv2_fused<<<dim3(13, 13, nb), 256, 0, stream>>>(Y1, w2, b2, Y2);
        conv3_fused<<<dim3(151, nb), 256, 0, stream>>>(Y2, w3, b3, X1, g);
    }

    // 4. symmetrize + softmax both maps (x0.5 folded in)
    symsoftmax<<<dim3(8, 2), 1024, 0, stream>>>(X0, X1);

    // 5. M = map0 + map1 (each already x0.5)
    combine_maps<<<dim3(1201), 256, 0, stream>>>(X0, X1, 307328);

    // 6. out[b] = M[b] @ x[b]           [196,196]x[196,2048], batched
    gemm_f32<<<dim3(32, 4, 8), 256, 0, stream>>>(
        X0, x, (float*)d_out, 196, 2048, 196, 196, 2048, 2048, nullptr,
        38416, 401408, 401408);
}

// Round 2
// 1353.027 us; speedup vs baseline: 3.4858x; 3.4858x over previous
//
#include <hip/hip_runtime.h>
#include <cmath>

#define N_TOK 196
#define NPX   38416
#define CDIM  256

typedef _Float16 f16;
typedef __attribute__((ext_vector_type(8))) _Float16 half8;
typedef __attribute__((ext_vector_type(4))) float f32x4;

// ---------------------------------------------------------------------------
// Generic fp32 GEMM: C = A@B (+bias), batched via grid.z with element strides.
// ---------------------------------------------------------------------------
__global__ __launch_bounds__(256) void gemm_f32(
    const float* __restrict__ A, const float* __restrict__ B, float* __restrict__ C,
    int M, int N, int K, int lda, int ldb, int ldc,
    const float* __restrict__ bias,
    long long sA, long long sB, long long sC)
{
    A += (long long)blockIdx.z * sA;
    B += (long long)blockIdx.z * sB;
    C += (long long)blockIdx.z * sC;
    __shared__ float As[16][68];
    __shared__ float Bs[16][68];
    int tid = threadIdx.x;
    int tx = tid & 15, ty = tid >> 4;
    int m0 = blockIdx.y * 64, n0 = blockIdx.x * 64;
    float acc[4][4] = {};
    for (int k0 = 0; k0 < K; k0 += 16) {
        __syncthreads();
        for (int e = tid; e < 1024; e += 256) {
            int m = e >> 4, kk = e & 15;
            int gm = m0 + m, gk = k0 + kk;
            As[kk][m] = (gm < M && gk < K) ? A[(long long)gm * lda + gk] : 0.f;
        }
        for (int e = tid; e < 1024; e += 256) {
            int kk = e >> 6, n = e & 63;
            int gk = k0 + kk, gn = n0 + n;
            Bs[kk][n] = (gk < K && gn < N) ? B[(long long)gk * ldb + gn] : 0.f;
        }
        __syncthreads();
        #pragma unroll
        for (int kk = 0; kk < 16; ++kk) {
            float4 av = *(const float4*)&As[kk][ty * 4];
            float4 bv = *(const float4*)&Bs[kk][tx * 4];
            float a[4] = {av.x, av.y, av.z, av.w};
            float b[4] = {bv.x, bv.y, bv.z, bv.w};
            #pragma unroll
            for (int u = 0; u < 4; ++u)
                #pragma unroll
                for (int v = 0; v < 4; ++v) acc[u][v] += a[u] * b[v];
        }
    }
    #pragma unroll
    for (int u = 0; u < 4; ++u) {
        int gm = m0 + ty * 4 + u;
        if (gm >= M) continue;
        #pragma unroll
        for (int v = 0; v < 4; ++v) {
            int gn = n0 + tx * 4 + v;
            if (gn >= N) continue;
            float val = acc[u][v];
            if (bias) val += bias[gn];
            C[(long long)gm * ldc + gn] = val;
        }
    }
}

// ---------------------------------------------------------------------------
// fp32 -> fp16 conversions
// ---------------------------------------------------------------------------
__global__ void cvt_f2h(const float* __restrict__ in, f16* __restrict__ out, int n)
{
    int e = blockIdx.x * 256 + threadIdx.x;
    if (e < n) out[e] = (f16)in[e];
}

// w [tap][Kc][D] fp32 -> wt [tap][D][Kc] fp16
__global__ void cvt_wt(const float* __restrict__ w, f16* __restrict__ wt,
                       int Kc, int D, int total)
{
    int e = blockIdx.x * 256 + threadIdx.x;
    if (e >= total) return;
    int td = Kc * D;
    int tap = e / td, r = e - tap * td;
    int c = r / D, d = r - c * D;
    wt[(size_t)(tap * D + d) * Kc + c] = (f16)w[e];
}

// ---------------------------------------------------------------------------
// Conv1 MFMA implicit-GEMM, pair built on the fly (A = SI_bcast * SJ_frag).
// Tile: 128 px (4 i x 32 j) x 128 d; K = 9 taps x 256 c. Output fp16.
// grid (7 jt, 49 it, 8 b), 256 thr (4 waves: wave w = i-row w of the tile).
// ---------------------------------------------------------------------------
__global__ __launch_bounds__(256, 2) void conv1_mfma(
    const f16* __restrict__ sub_h,   // [8][196][256]
    const f16* __restrict__ w1t,     // [9][128][256]
    const float* __restrict__ b1,    // [128]
    f16* __restrict__ Y1h)           // [8][196][196][128]
{
    __shared__ f16 sh[17408];        // 34816 B
    f16* SJ = sh;                    // [34][264]  (pad: 2-way bank only)
    f16* SI = sh + 8976;             // [6][256]
    f16* BW = sh + 10512;            // [128][40]  (pad 40: kills 8-way)
    f16* OT = sh;                    // epilogue [128][136]

    int b = blockIdx.z;
    int i0 = blockIdx.y * 4, j0 = blockIdx.x * 32;
    int tid = threadIdx.x;
    const f16* subB = sub_h + (size_t)b * N_TOK * CDIM;

    uint4 zz = make_uint4(0, 0, 0, 0);
    for (int e = tid; e < 1088; e += 256) {      // SJ: rows j0-1 .. j0+32
        int r = e >> 5, q = e & 31;
        int gj = j0 - 1 + r;
        uint4 v = zz;
        if (gj >= 0 && gj < N_TOK) v = *(const uint4*)(subB + gj * CDIM + q * 8);
        *(uint4*)(SJ + r * 264 + q * 8) = v;
    }
    if (tid < 192) {                              // SI: rows i0-1 .. i0+4
        int r = tid >> 5, q = tid & 31;
        int gi = i0 - 1 + r;
        uint4 v = zz;
        if (gi >= 0 && gi < N_TOK) v = *(const uint4*)(subB + gi * CDIM + q * 8);
        *(uint4*)(SI + r * 256 + q * 8) = v;
    }

    int wave = tid >> 6, lane = tid & 63;
    int quad = lane >> 4, l16 = lane & 15;
    int ii = wave;                                // px = ii*32 + jj

    f32x4 zero = {0.f, 0.f, 0.f, 0.f};
    f32x4 acc[2][8];
    #pragma unroll
    for (int t = 0; t < 2; ++t)
        #pragma unroll
        for (int n = 0; n < 8; ++n) acc[t][n] = zero;

    for (int tap = 0; tap < 9; ++tap) {
        int di = tap / 3 - 1, dj = tap % 3 - 1;
        for (int c0 = 0; c0 < 256; c0 += 32) {
            __syncthreads();
            for (int e = tid; e < 512; e += 256) {    // stage B chunk [128 d][32 c]
                int d = e >> 2, q = e & 3;
                *(uint4*)(BW + d * 40 + q * 8) =
                    *(const uint4*)(w1t + (size_t)(tap * 128 + d) * 256 + c0 + q * 8);
            }
            __syncthreads();
            half8 sib = *(const half8*)(SI + (ii + di + 1) * 256 + c0 + quad * 8);
            half8 a0 = sib * *(const half8*)(SJ + (l16 + dj + 1) * 264 + c0 + quad * 8);
            half8 a1 = sib * *(const half8*)(SJ + (l16 + 16 + dj + 1) * 264 + c0 + quad * 8);
            half8 bf[8];
            #pragma unroll
            for (int n = 0; n < 8; ++n)
                bf[n] = *(const half8*)(BW + (n * 16 + l16) * 40 + quad * 8);
            #pragma unroll
            for (int n = 0; n < 8; ++n) {
                acc[0][n] = __builtin_amdgcn_mfma_f32_16x16x32_f16(a0, bf[n], acc[0][n], 0, 0, 0);
                acc[1][n] = __builtin_amdgcn_mfma_f32_16x16x32_f16(a1, bf[n], acc[1][n], 0, 0, 0);
            }
        }
    }
    __syncthreads();
    // epilogue: bias + relu -> fp16 via LDS bounce (C layout: col=l16, row=quad*4+r)
    #pragma unroll
    for (int t = 0; t < 2; ++t)
        #pragma unroll
        for (int n = 0; n < 8; ++n) {
            int d = n * 16 + l16;
            float bias = b1[d];
            #pragma unroll
            for (int r = 0; r < 4; ++r) {
                int px = ii * 32 + t * 16 + quad * 4 + r;
                OT[px * 136 + d] = (f16)fmaxf(acc[t][n][r] + bias, 0.f);
            }
        }
    __syncthreads();
    f16* Yb = Y1h + (size_t)b * NPX * 128;
    for (int e = tid; e < 2048; e += 256) {
        int px = e >> 4, q = e & 15;
        int i = i0 + (px >> 5), j = j0 + (px & 31);
        if (j < N_TOK)
            *(uint4*)(Yb + ((size_t)i * N_TOK + j) * 128 + q * 8) =
                *(const uint4*)(OT + px * 136 + q * 8);
    }
}

// ---------------------------------------------------------------------------
// Conv2 MFMA: 3x3 dil (1,2), 128->64, fp16 in/out.
// Tile: 64 px (2 i x 32 j) x 64 d; K = 9 x 128. grid (7 jt, 98 it, 8 b).
// ---------------------------------------------------------------------------
__global__ __launch_bounds__(256, 2) void conv2_mfma(
    const f16* __restrict__ Y1h, const f16* __restrict__ w2t,
    const float* __restrict__ b2, f16* __restrict__ Y2h)
{
    __shared__ f16 sh[22144];        // 44288 B
    f16* Ys = sh;                    // [4][36][136]
    f16* BW = sh + 19584;            // [64][40]
    f16* OT = sh;                    // epilogue [64][72]

    int b = blockIdx.z;
    int i0 = blockIdx.y * 2, j0 = blockIdx.x * 32;
    int tid = threadIdx.x;
    const f16* Yb = Y1h + (size_t)b * NPX * 128;

    uint4 zz = make_uint4(0, 0, 0, 0);
    for (int e = tid; e < 2304; e += 256) {   // rows i0-1..i0+2, cols j0-2..j0+33
        int ir = e / 576, rem = e - ir * 576;
        int jq = rem >> 4, q = rem & 15;
        int gi = i0 - 1 + ir, gj = j0 - 2 + jq;
        uint4 v = zz;
        if (gi >= 0 && gi < N_TOK && gj >= 0 && gj < N_TOK)
            v = *(const uint4*)(Yb + ((size_t)gi * N_TOK + gj) * 128 + q * 8);
        *(uint4*)(Ys + (ir * 36 + jq) * 136 + q * 8) = v;
    }

    int wave = tid >> 6, lane = tid & 63;
    int quad = lane >> 4, l16 = lane & 15;
    int ii = wave >> 1, jb = (wave & 1) * 16;

    f32x4 zero = {0.f, 0.f, 0.f, 0.f};
    f32x4 acc[4] = {zero, zero, zero, zero};

    for (int tap = 0; tap < 9; ++tap) {
        int di = tap / 3 - 1, dj2 = (tap % 3 - 1) * 2;
        for (int c0 = 0; c0 < 128; c0 += 32) {
            __syncthreads();
            {
                int d = tid >> 2, q = tid & 3;
                if (tid < 256)
                    *(uint4*)(BW + d * 40 + q * 8) =
                        *(const uint4*)(w2t + (size_t)(tap * 64 + d) * 128 + c0 + q * 8);
            }
            __syncthreads();
            half8 a = *(const half8*)(Ys + ((ii + di + 1) * 36 + jb + l16 + dj2 + 2) * 136
                                      + c0 + quad * 8);
            #pragma unroll
            for (int n = 0; n < 4; ++n) {
                half8 bf = *(const half8*)(BW + (n * 16 + l16) * 40 + quad * 8);
                acc[n] = __builtin_amdgcn_mfma_f32_16x16x32_f16(a, bf, acc[n], 0, 0, 0);
            }
        }
    }
    __syncthreads();
    #pragma unroll
    for (int n = 0; n < 4; ++n) {
        int d = n * 16 + l16;
        float bias = b2[d];
        #pragma unroll
        for (int r = 0; r < 4; ++r) {
            int px = ii * 32 + jb + quad * 4 + r;
            OT[px * 72 + d] = (f16)fmaxf(acc[n][r] + bias, 0.f);
        }
    }
    __syncthreads();
    f16* Zb = Y2h + (size_t)b * NPX * 64;
    for (int e = tid; e < 512; e += 256) {
        int px = e >> 3, q = e & 7;
        int i = i0 + (px >> 5), j = j0 + (px & 31);
        if (j < N_TOK)
            *(uint4*)(Zb + ((size_t)i * N_TOK + j) * 64 + q * 8) =
                *(const uint4*)(OT + px * 72 + q * 8);
    }
}

// ---------------------------------------------------------------------------
// Conv3: 3x3 dil (1,4), 64->1, fp16 input, fp32 accumulate -> X1 logits.
// ---------------------------------------------------------------------------
__global__ __launch_bounds__(256) void conv3_h(
    const f16* __restrict__ Y2h, const float* __restrict__ w3,
    const float* __restrict__ b3, float* __restrict__ X1)
{
    __shared__ float w[576];
    int b = blockIdx.y;
    const f16* Yb = Y2h + (size_t)b * NPX * 64;
    for (int e = threadIdx.x; e < 576; e += 256) w[e] = w3[e];
    __syncthreads();
    int px = blockIdx.x * 256 + threadIdx.x;
    if (px >= NPX) return;
    int i = px / 196, j = px - i * 196;
    float s = b3[0];
    for (int tap = 0; tap < 9; ++tap) {
        int gi = i + tap / 3 - 1, gj = j + (tap % 3 - 1) * 4;
        if (gi < 0 || gi >= N_TOK || gj < 0 || gj >= N_TOK) continue;
        const half8* src = (const half8*)(Yb + ((size_t)gi * N_TOK + gj) * 64);
        const float* wt = w + tap * 64;
        #pragma unroll
        for (int q = 0; q < 8; ++q) {
            half8 h = src[q];
            #pragma unroll
            for (int e = 0; e < 8; ++e) s += (float)h[e] * wt[q * 8 + e];
        }
    }
    X1[(size_t)b * NPX + px] = fmaxf(s, 0.f);
}

// ---------------------------------------------------------------------------
// Branch 0: fused pair -> 1x1 conv stack (unchanged fp32 path).
// ---------------------------------------------------------------------------
__global__ __launch_bounds__(256, 2) void branch0_fused(
    const float* __restrict__ sub,
    const float* __restrict__ w01, const float* __restrict__ b01,
    const float* __restrict__ w02, const float* __restrict__ b02,
    const float* __restrict__ w03, const float* __restrict__ b03,
    float* __restrict__ X0)
{
    __shared__ float U[6208];
    __shared__ float H1[64][129];
    __shared__ float W3s[64];
    float* Si  = U;
    float* Sj  = U + 2064;
    float* Ws  = U + 4128;
    float* W2s = U;
    float* H2  = U + 2048;

    int b = blockIdx.z;
    int i0 = blockIdx.y * 8, j0 = blockIdx.x * 8;
    const float* subB = sub + (long long)b * N_TOK * CDIM;
    int tid = threadIdx.x;

    for (int e = tid; e < 8 * 256; e += 256) {
        int r = e >> 8, c = e & 255;
        int gi = i0 + r;
        Si[r * 258 + c] = (gi < N_TOK) ? subB[gi * CDIM + c] : 0.f;
        int gj = j0 + r;
        Sj[r * 258 + c] = (gj < N_TOK) ? subB[gj * CDIM + c] : 0.f;
    }
    if (tid < 64) W3s[tid] = w03[tid];

    int pxg = tid & 31;
    int dg  = tid >> 5;
    int d0  = dg * 16;
    int ti  = pxg >> 3, tj = pxg & 7;

    float4 acc[2][4];
    #pragma unroll
    for (int p = 0; p < 2; ++p)
        #pragma unroll
        for (int q = 0; q < 4; ++q) acc[p][q] = make_float4(0.f, 0.f, 0.f, 0.f);

    const float* arow0 = Si + ti * 258;
    const float* arow1 = Si + (ti + 4) * 258;
    const float* brow  = Sj + tj * 258;

    for (int c0 = 0; c0 < 256; c0 += 16) {
        __syncthreads();
        for (int e = tid; e < 2048; e += 256) {
            int cc = e >> 7, dd = e & 127;
            Ws[cc * 128 + dd] = w01[(c0 + cc) * 128 + dd];
        }
        __syncthreads();
        #pragma unroll 4
        for (int cc = 0; cc < 16; ++cc) {
            int c = c0 + cc;
            float bj = brow[c];
            float pA = arow0[c] * bj;
            float pB = arow1[c] * bj;
            const float4* wr = (const float4*)(Ws + cc * 128 + d0);
            #pragma unroll
            for (int q = 0; q < 4; ++q) {
                float4 w4 = wr[q];
                acc[0][q].x += pA * w4.x; acc[0][q].y += pA * w4.y;
                acc[0][q].z += pA * w4.z; acc[0][q].w += pA * w4.w;
                acc[1][q].x += pB * w4.x; acc[1][q].y += pB * w4.y;
                acc[1][q].z += pB * w4.z; acc[1][q].w += pB * w4.w;
            }
        }
    }
    {
        const float4* bb4 = (const float4*)(b01 + d0);
        float4 bv[4] = {bb4[0], bb4[1], bb4[2], bb4[3]};
        #pragma unroll
        for (int p = 0; p < 2; ++p) {
            int px = pxg + 32 * p;
            float* h = &H1[px][d0];
            #pragma unroll
            for (int q = 0; q < 4; ++q) {
                h[q * 4 + 0] = fmaxf(acc[p][q].x + bv[q].x, 0.f);
                h[q * 4 + 1] = fmaxf(acc[p][q].y + bv[q].y, 0.f);
                h[q * 4 + 2] = fmaxf(acc[p][q].z + bv[q].z, 0.f);
                h[q * 4 + 3] = fmaxf(acc[p][q].w + bv[q].w, 0.f);
            }
        }
    }
    int e0 = dg * 8;
    float4 acc2[2][2];
    #pragma unroll
    for (int p = 0; p < 2; ++p)
        #pragma unroll
        for (int q = 0; q < 2; ++q) acc2[p][q] = make_float4(0.f, 0.f, 0.f, 0.f);

    for (int c0 = 0; c0 < 128; c0 += 32) {
        __syncthreads();
        for (int e = tid; e < 2048; e += 256) {
            int cc = e >> 6, ee = e & 63;
            W2s[cc * 64 + ee] = w02[(c0 + cc) * 64 + ee];
        }
        __syncthreads();
        #pragma unroll 4
        for (int cc = 0; cc < 32; ++cc) {
            int c = c0 + cc;
            float hA = H1[pxg][c];
            float hB = H1[pxg + 32][c];
            const float4* wr = (const float4*)(W2s + cc * 64 + e0);
            float4 w0 = wr[0], w1 = wr[1];
            acc2[0][0].x += hA * w0.x; acc2[0][0].y += hA * w0.y;
            acc2[0][0].z += hA * w0.z; acc2[0][0].w += hA * w0.w;
            acc2[0][1].x += hA * w1.x; acc2[0][1].y += hA * w1.y;
            acc2[0][1].z += hA * w1.z; acc2[0][1].w += hA * w1.w;
            acc2[1][0].x += hB * w0.x; acc2[1][0].y += hB * w0.y;
            acc2[1][0].z += hB * w0.z; acc2[1][0].w += hB * w0.w;
            acc2[1][1].x += hB * w1.x; acc2[1][1].y += hB * w1.y;
            acc2[1][1].z += hB * w1.z; acc2[1][1].w += hB * w1.w;
        }
    }
    {
        #pragma unroll
        for (int p = 0; p < 2; ++p) {
            int px = pxg + 32 * p;
            float* h = H2 + px * 65 + e0;
            h[0] = fmaxf(acc2[p][0].x + b02[e0 + 0], 0.f);
            h[1] = fmaxf(acc2[p][0].y + b02[e0 + 1], 0.f);
            h[2] = fmaxf(acc2[p][0].z + b02[e0 + 2], 0.f);
            h[3] = fmaxf(acc2[p][0].w + b02[e0 + 3], 0.f);
            h[4] = fmaxf(acc2[p][1].x + b02[e0 + 4], 0.f);
            h[5] = fmaxf(acc2[p][1].y + b02[e0 + 5], 0.f);
            h[6] = fmaxf(acc2[p][1].z + b02[e0 + 6], 0.f);
            h[7] = fmaxf(acc2[p][1].w + b02[e0 + 7], 0.f);
        }
    }
    __syncthreads();
    if (tid < 64) {
        float s = b03[0];
        const float* h = H2 + tid * 65;
        #pragma unroll 8
        for (int c = 0; c < 64; ++c) s += h[c] * W3s[c];
        int i = i0 + (tid >> 3), j = j0 + (tid & 7);
        if (i < N_TOK && j < N_TOK)
            X0[(long long)b * NPX + i * N_TOK + j] = fmaxf(s, 0.f);
    }
}

// ---------------------------------------------------------------------------
// Symmetrize + softmax over 38416 logits, /2 folded in.
// ---------------------------------------------------------------------------
__global__ __launch_bounds__(1024) void symsoftmax(float* __restrict__ X0,
                                                   float* __restrict__ X1)
{
    __shared__ float red[32];
    __shared__ float red2[32];
    float* X = (blockIdx.y ? X1 : X0) + (long long)blockIdx.x * NPX;
    int tid = threadIdx.x;
    float v[38];
    float mx = -3.0e38f;
    #pragma unroll
    for (int p = 0; p < 38; ++p) {
        int e = tid + p * 1024;
        if (e < NPX) {
            int i = e / 196, j = e - i * 196;
            float t = X[e] + X[j * 196 + i];
            v[p] = t;
            mx = fmaxf(mx, t);
        } else v[p] = -3.0e38f;
    }
    #pragma unroll
    for (int off = 32; off > 0; off >>= 1) mx = fmaxf(mx, __shfl_xor(mx, off));
    if ((tid & 63) == 0) red[tid >> 6] = mx;
    __syncthreads();
    if (tid < 64) {
        float m = (tid < 16) ? red[tid] : -3.0e38f;
        #pragma unroll
        for (int off = 8; off > 0; off >>= 1) m = fmaxf(m, __shfl_xor(m, off));
        if (tid == 0) red[0] = m;
    }
    __syncthreads();
    mx = red[0];
    float s = 0.f;
    #pragma unroll
    for (int p = 0; p < 38; ++p) {
        int e = tid + p * 1024;
        float ex = (e < NPX) ? expf(v[p] - mx) : 0.f;
        v[p] = ex;
        s += ex;
    }
    #pragma unroll
    for (int off = 32; off > 0; off >>= 1) s += __shfl_xor(s, off);
    if ((tid & 63) == 0) red2[tid >> 6] = s;
    __syncthreads();
    if (tid < 64) {
        float m = (tid < 16) ? red2[tid] : 0.f;
        #pragma unroll
        for (int off = 8; off > 0; off >>= 1) m += __shfl_xor(m, off);
        if (tid == 0) red2[0] = m;
    }
    __syncthreads();
    float scale = 0.5f / red2[0];
    #pragma unroll
    for (int p = 0; p < 38; ++p) {
        int e = tid + p * 1024;
        if (e < NPX) X[e] = v[p] * scale;
    }
}

__global__ void combine_maps(float* __restrict__ X0, const float* __restrict__ X1, int n)
{
    int e = blockIdx.x * 256 + threadIdx.x;
    if (e < n) X0[e] += X1[e];
}

// ---------------------------------------------------------------------------
extern "C" void kernel_launch(void* const* d_in, const int* in_sizes, int n_in,
                              void* d_out, int out_size, void* d_ws, size_t ws_size,
                              hipStream_t stream)
{
    (void)in_sizes; (void)n_in; (void)out_size; (void)ws_size;
    const float* x     = (const float*)d_in[0];
    const float* w_prj = (const float*)d_in[1];
    const float* b_prj = (const float*)d_in[2];
    const float* w01   = (const float*)d_in[3];
    const float* b01   = (const float*)d_in[4];
    const float* w02   = (const float*)d_in[5];
    const float* b02   = (const float*)d_in[6];
    const float* w03   = (const float*)d_in[7];
    const float* b03   = (const float*)d_in[8];
    const float* w1    = (const float*)d_in[9];
    const float* b1    = (const float*)d_in[10];
    const float* w2    = (const float*)d_in[11];
    const float* b2    = (const float*)d_in[12];
    const float* w3    = (const float*)d_in[13];
    const float* b3    = (const float*)d_in[14];

    char* W = (char*)d_ws;
    float* sub  = (float*)(W + 0);          // 401408 f
    float* X0   = (float*)(W + 1605632);    // 307328 f
    float* X1   = (float*)(W + 2834944);    // 307328 f
    f16*   subh = (f16*)(W + 4064256);      // 401408 h
    f16*   w1t  = (f16*)(W + 4867072);      // 294912 h
    f16*   w2t  = (f16*)(W + 5456896);      // 73728 h
    f16*   Y1h  = (f16*)(W + 5604352);      // 8*38416*128 h = 78.7 MB
    f16*   Y2h  = (f16*)(W + 84280320);     // 8*38416*64 h  = 39.3 MB (end ~124 MB)

    // 1. sub = x @ w_prj + b_prj
    gemm_f32<<<dim3(4, 25, 1), 256, 0, stream>>>(
        x, w_prj, sub, 1568, 256, 2048, 2048, 256, 256, b_prj, 0, 0, 0);

    // 2. fp16 conversions
    cvt_f2h<<<dim3(1568), 256, 0, stream>>>(sub, subh, 401408);
    cvt_wt<<<dim3(1152), 256, 0, stream>>>(w1, w1t, 256, 128, 294912);
    cvt_wt<<<dim3(288),  256, 0, stream>>>(w2, w2t, 128, 64, 73728);

    // 3. branch 0 -> X0 logits (fp32)
    branch0_fused<<<dim3(25, 25, 8), 256, 0, stream>>>(
        sub, w01, b01, w02, b02, w03, b03, X0);

    // 4. conv branch (MFMA fp16) -> X1 logits
    conv1_mfma<<<dim3(7, 49, 8), 256, 0, stream>>>(subh, w1t, b1, Y1h);
    conv2_mfma<<<dim3(7, 98, 8), 256, 0, stream>>>(Y1h, w2t, b2, Y2h);
    conv3_h<<<dim3(151, 8), 256, 0, stream>>>(Y2h, w3, b3, X1);

    // 5. symmetrize + softmax both maps (x0.5 folded in)
    symsoftmax<<<dim3(8, 2), 1024, 0, stream>>>(X0, X1);

    // 6. M = map0 + map1
    combine_maps<<<dim3(1201), 256, 0, stream>>>(X0, X1, 307328);

    // 7. out[b] = M[b] @ x[b]
    gemm_f32<<<dim3(32, 4, 8), 256, 0, stream>>>(
        X0, x, (float*)d_out, 196, 2048, 196, 196, 2048, 2048, nullptr,
        38416, 401408, 401408);
}

// Round 3
// 935.557 us; speedup vs baseline: 5.0413x; 1.4462x over previous
//
#include <hip/hip_runtime.h>
#include <cmath>

#define N_TOK 196
#define NPX   38416
#define CDIM  256

typedef _Float16 f16;
typedef __attribute__((ext_vector_type(8))) _Float16 half8;
typedef __attribute__((ext_vector_type(4))) float f32x4;

// ---------------------------------------------------------------------------
// Generic fp32 GEMM: C = A@B (+bias), batched via grid.z with element strides.
// ---------------------------------------------------------------------------
__global__ __launch_bounds__(256) void gemm_f32(
    const float* __restrict__ A, const float* __restrict__ B, float* __restrict__ C,
    int M, int N, int K, int lda, int ldb, int ldc,
    const float* __restrict__ bias,
    long long sA, long long sB, long long sC)
{
    A += (long long)blockIdx.z * sA;
    B += (long long)blockIdx.z * sB;
    C += (long long)blockIdx.z * sC;
    __shared__ float As[16][68];
    __shared__ float Bs[16][68];
    int tid = threadIdx.x;
    int tx = tid & 15, ty = tid >> 4;
    int m0 = blockIdx.y * 64, n0 = blockIdx.x * 64;
    float acc[4][4] = {};
    for (int k0 = 0; k0 < K; k0 += 16) {
        __syncthreads();
        for (int e = tid; e < 1024; e += 256) {
            int m = e >> 4, kk = e & 15;
            int gm = m0 + m, gk = k0 + kk;
            As[kk][m] = (gm < M && gk < K) ? A[(long long)gm * lda + gk] : 0.f;
        }
        for (int e = tid; e < 1024; e += 256) {
            int kk = e >> 6, n = e & 63;
            int gk = k0 + kk, gn = n0 + n;
            Bs[kk][n] = (gk < K && gn < N) ? B[(long long)gk * ldb + gn] : 0.f;
        }
        __syncthreads();
        #pragma unroll
        for (int kk = 0; kk < 16; ++kk) {
            float4 av = *(const float4*)&As[kk][ty * 4];
            float4 bv = *(const float4*)&Bs[kk][tx * 4];
            float a[4] = {av.x, av.y, av.z, av.w};
            float b[4] = {bv.x, bv.y, bv.z, bv.w};
            #pragma unroll
            for (int u = 0; u < 4; ++u)
                #pragma unroll
                for (int v = 0; v < 4; ++v) acc[u][v] += a[u] * b[v];
        }
    }
    #pragma unroll
    for (int u = 0; u < 4; ++u) {
        int gm = m0 + ty * 4 + u;
        if (gm >= M) continue;
        #pragma unroll
        for (int v = 0; v < 4; ++v) {
            int gn = n0 + tx * 4 + v;
            if (gn >= N) continue;
            float val = acc[u][v];
            if (bias) val += bias[gn];
            C[(long long)gm * ldc + gn] = val;
        }
    }
}

// ---------------------------------------------------------------------------
// fp32 -> fp16 conversions
// ---------------------------------------------------------------------------
__global__ void cvt_f2h(const float* __restrict__ in, f16* __restrict__ out, int n)
{
    int e = blockIdx.x * 256 + threadIdx.x;
    if (e < n) out[e] = (f16)in[e];
}

// w [tap][Kc][D] fp32 -> wt [tap][D][Kc] fp16  (tap=1 gives plain transpose)
__global__ void cvt_wt(const float* __restrict__ w, f16* __restrict__ wt,
                       int Kc, int D, int total)
{
    int e = blockIdx.x * 256 + threadIdx.x;
    if (e >= total) return;
    int td = Kc * D;
    int tap = e / td, r = e - tap * td;
    int c = r / D, d = r - c * D;
    wt[(size_t)(tap * D + d) * Kc + c] = (f16)w[e];
}

// ---------------------------------------------------------------------------
// Conv1 MFMA implicit-GEMM, pair built on the fly (A = SI_bcast * SJ_frag).
// Tile: 128 px (4 i x 32 j) x 128 d; K = 9 taps x 256 c. Output fp16.
// ---------------------------------------------------------------------------
__global__ __launch_bounds__(256, 2) void conv1_mfma(
    const f16* __restrict__ sub_h,   // [8][196][256]
    const f16* __restrict__ w1t,     // [9][128][256]
    const float* __restrict__ b1,    // [128]
    f16* __restrict__ Y1h)           // [8][196][196][128]
{
    __shared__ f16 sh[17408];        // 34816 B
    f16* SJ = sh;                    // [34][264]
    f16* SI = sh + 8976;             // [6][256]
    f16* BW = sh + 10512;            // [128][40]
    f16* OT = sh;                    // epilogue [128][136]

    int b = blockIdx.z;
    int i0 = blockIdx.y * 4, j0 = blockIdx.x * 32;
    int tid = threadIdx.x;
    const f16* subB = sub_h + (size_t)b * N_TOK * CDIM;

    uint4 zz = make_uint4(0, 0, 0, 0);
    for (int e = tid; e < 1088; e += 256) {
        int r = e >> 5, q = e & 31;
        int gj = j0 - 1 + r;
        uint4 v = zz;
        if (gj >= 0 && gj < N_TOK) v = *(const uint4*)(subB + gj * CDIM + q * 8);
        *(uint4*)(SJ + r * 264 + q * 8) = v;
    }
    if (tid < 192) {
        int r = tid >> 5, q = tid & 31;
        int gi = i0 - 1 + r;
        uint4 v = zz;
        if (gi >= 0 && gi < N_TOK) v = *(const uint4*)(subB + gi * CDIM + q * 8);
        *(uint4*)(SI + r * 256 + q * 8) = v;
    }

    int wave = tid >> 6, lane = tid & 63;
    int quad = lane >> 4, l16 = lane & 15;
    int ii = wave;

    f32x4 zero = {0.f, 0.f, 0.f, 0.f};
    f32x4 acc[2][8];
    #pragma unroll
    for (int t = 0; t < 2; ++t)
        #pragma unroll
        for (int n = 0; n < 8; ++n) acc[t][n] = zero;

    for (int tap = 0; tap < 9; ++tap) {
        int di = tap / 3 - 1, dj = tap % 3 - 1;
        for (int c0 = 0; c0 < 256; c0 += 32) {
            __syncthreads();
            for (int e = tid; e < 512; e += 256) {
                int d = e >> 2, q = e & 3;
                *(uint4*)(BW + d * 40 + q * 8) =
                    *(const uint4*)(w1t + (size_t)(tap * 128 + d) * 256 + c0 + q * 8);
            }
            __syncthreads();
            half8 sib = *(const half8*)(SI + (ii + di + 1) * 256 + c0 + quad * 8);
            half8 a0 = sib * *(const half8*)(SJ + (l16 + dj + 1) * 264 + c0 + quad * 8);
            half8 a1 = sib * *(const half8*)(SJ + (l16 + 16 + dj + 1) * 264 + c0 + quad * 8);
            half8 bf[8];
            #pragma unroll
            for (int n = 0; n < 8; ++n)
                bf[n] = *(const half8*)(BW + (n * 16 + l16) * 40 + quad * 8);
            #pragma unroll
            for (int n = 0; n < 8; ++n) {
                acc[0][n] = __builtin_amdgcn_mfma_f32_16x16x32_f16(a0, bf[n], acc[0][n], 0, 0, 0);
                acc[1][n] = __builtin_amdgcn_mfma_f32_16x16x32_f16(a1, bf[n], acc[1][n], 0, 0, 0);
            }
        }
    }
    __syncthreads();
    #pragma unroll
    for (int t = 0; t < 2; ++t)
        #pragma unroll
        for (int n = 0; n < 8; ++n) {
            int d = n * 16 + l16;
            float bias = b1[d];
            #pragma unroll
            for (int r = 0; r < 4; ++r) {
                int px = ii * 32 + t * 16 + quad * 4 + r;
                OT[px * 136 + d] = (f16)fmaxf(acc[t][n][r] + bias, 0.f);
            }
        }
    __syncthreads();
    f16* Yb = Y1h + (size_t)b * NPX * 128;
    for (int e = tid; e < 2048; e += 256) {
        int px = e >> 4, q = e & 15;
        int i = i0 + (px >> 5), j = j0 + (px & 31);
        if (j < N_TOK)
            *(uint4*)(Yb + ((size_t)i * N_TOK + j) * 128 + q * 8) =
                *(const uint4*)(OT + px * 136 + q * 8);
    }
}

// ---------------------------------------------------------------------------
// Conv2 MFMA: 3x3 dil (1,2), 128->64, fp16 in/out.
// ---------------------------------------------------------------------------
__global__ __launch_bounds__(256, 2) void conv2_mfma(
    const f16* __restrict__ Y1h, const f16* __restrict__ w2t,
    const float* __restrict__ b2, f16* __restrict__ Y2h)
{
    __shared__ f16 sh[22144];
    f16* Ys = sh;                    // [4][36][136]
    f16* BW = sh + 19584;            // [64][40]
    f16* OT = sh;                    // epilogue [64][72]

    int b = blockIdx.z;
    int i0 = blockIdx.y * 2, j0 = blockIdx.x * 32;
    int tid = threadIdx.x;
    const f16* Yb = Y1h + (size_t)b * NPX * 128;

    uint4 zz = make_uint4(0, 0, 0, 0);
    for (int e = tid; e < 2304; e += 256) {
        int ir = e / 576, rem = e - ir * 576;
        int jq = rem >> 4, q = rem & 15;
        int gi = i0 - 1 + ir, gj = j0 - 2 + jq;
        uint4 v = zz;
        if (gi >= 0 && gi < N_TOK && gj >= 0 && gj < N_TOK)
            v = *(const uint4*)(Yb + ((size_t)gi * N_TOK + gj) * 128 + q * 8);
        *(uint4*)(Ys + (ir * 36 + jq) * 136 + q * 8) = v;
    }

    int wave = tid >> 6, lane = tid & 63;
    int quad = lane >> 4, l16 = lane & 15;
    int ii = wave >> 1, jb = (wave & 1) * 16;

    f32x4 zero = {0.f, 0.f, 0.f, 0.f};
    f32x4 acc[4] = {zero, zero, zero, zero};

    for (int tap = 0; tap < 9; ++tap) {
        int di = tap / 3 - 1, dj2 = (tap % 3 - 1) * 2;
        for (int c0 = 0; c0 < 128; c0 += 32) {
            __syncthreads();
            {
                int d = tid >> 2, q = tid & 3;
                *(uint4*)(BW + d * 40 + q * 8) =
                    *(const uint4*)(w2t + (size_t)(tap * 64 + d) * 128 + c0 + q * 8);
            }
            __syncthreads();
            half8 a = *(const half8*)(Ys + ((ii + di + 1) * 36 + jb + l16 + dj2 + 2) * 136
                                      + c0 + quad * 8);
            #pragma unroll
            for (int n = 0; n < 4; ++n) {
                half8 bf = *(const half8*)(BW + (n * 16 + l16) * 40 + quad * 8);
                acc[n] = __builtin_amdgcn_mfma_f32_16x16x32_f16(a, bf, acc[n], 0, 0, 0);
            }
        }
    }
    __syncthreads();
    #pragma unroll
    for (int n = 0; n < 4; ++n) {
        int d = n * 16 + l16;
        float bias = b2[d];
        #pragma unroll
        for (int r = 0; r < 4; ++r) {
            int px = ii * 32 + jb + quad * 4 + r;
            OT[px * 72 + d] = (f16)fmaxf(acc[n][r] + bias, 0.f);
        }
    }
    __syncthreads();
    f16* Zb = Y2h + (size_t)b * NPX * 64;
    for (int e = tid; e < 512; e += 256) {
        int px = e >> 3, q = e & 7;
        int i = i0 + (px >> 5), j = j0 + (px & 31);
        if (j < N_TOK)
            *(uint4*)(Zb + ((size_t)i * N_TOK + j) * 64 + q * 8) =
                *(const uint4*)(OT + px * 72 + q * 8);
    }
}

// ---------------------------------------------------------------------------
// Conv3: 3x3 dil (1,4), 64->1, fp16 input, fp32 accumulate -> X1 logits.
// ---------------------------------------------------------------------------
__global__ __launch_bounds__(256) void conv3_h(
    const f16* __restrict__ Y2h, const float* __restrict__ w3,
    const float* __restrict__ b3, float* __restrict__ X1)
{
    __shared__ float w[576];
    int b = blockIdx.y;
    const f16* Yb = Y2h + (size_t)b * NPX * 64;
    for (int e = threadIdx.x; e < 576; e += 256) w[e] = w3[e];
    __syncthreads();
    int px = blockIdx.x * 256 + threadIdx.x;
    if (px >= NPX) return;
    int i = px / 196, j = px - i * 196;
    float s = b3[0];
    for (int tap = 0; tap < 9; ++tap) {
        int gi = i + tap / 3 - 1, gj = j + (tap % 3 - 1) * 4;
        if (gi < 0 || gi >= N_TOK || gj < 0 || gj >= N_TOK) continue;
        const half8* src = (const half8*)(Yb + ((size_t)gi * N_TOK + gj) * 64);
        const float* wt = w + tap * 64;
        #pragma unroll
        for (int q = 0; q < 8; ++q) {
            half8 h = src[q];
            #pragma unroll
            for (int e = 0; e < 8; ++e) s += (float)h[e] * wt[q * 8 + e];
        }
    }
    X1[(size_t)b * NPX + px] = fmaxf(s, 0.f);
}

// ---------------------------------------------------------------------------
// Branch 0 MFMA: pair -> 1x1 stack 256->128->64->1, all in one block.
// Tile 128 px (4 i x 32 j). Layer1/2 on matrix cores, layer3 VALU.
// LDS: SJ[32][264] + SI[4][256] + BW[128][40] + H1[128][136] = 62.75 KB.
// H2[128][72] aliases SJ/SI (dead after layer 1).
// ---------------------------------------------------------------------------
__global__ __launch_bounds__(256, 2) void branch0_mfma(
    const f16* __restrict__ sub_h,   // [8][196][256]
    const f16* __restrict__ w01t,    // [128][256]
    const float* __restrict__ b01,
    const f16* __restrict__ w02t,    // [64][128]
    const float* __restrict__ b02,
    const float* __restrict__ w03, const float* __restrict__ b03,
    float* __restrict__ X0)
{
    __shared__ f16 sh[32000];
    __shared__ float W3s[64];
    f16* SJ = sh;            // [32][264] = 8448
    f16* SI = sh + 8448;     // [4][256]  = 1024
    f16* BW = sh + 9472;     // [128][40] = 5120
    f16* H1 = sh + 14592;    // [128][136]= 17408
    f16* H2 = sh;            // [128][72] = 9216 (aliases SJ/SI)

    int b = blockIdx.z;
    int i0 = blockIdx.y * 4, j0 = blockIdx.x * 32;
    int tid = threadIdx.x;
    const f16* subB = sub_h + (size_t)b * N_TOK * CDIM;

    uint4 zz = make_uint4(0, 0, 0, 0);
    for (int e = tid; e < 1024; e += 256) {       // SJ rows j0..j0+31
        int r = e >> 5, q = e & 31;
        int gj = j0 + r;
        uint4 v = zz;
        if (gj < N_TOK) v = *(const uint4*)(subB + gj * CDIM + q * 8);
        *(uint4*)(SJ + r * 264 + q * 8) = v;
    }
    if (tid < 128) {                               // SI rows i0..i0+3
        int r = tid >> 5, q = tid & 31;
        int gi = i0 + r;
        uint4 v = zz;
        if (gi < N_TOK) v = *(const uint4*)(subB + gi * CDIM + q * 8);
        *(uint4*)(SI + r * 256 + q * 8) = v;
    }
    if (tid < 64) W3s[tid] = w03[tid];

    int wave = tid >> 6, lane = tid & 63;
    int quad = lane >> 4, l16 = lane & 15;
    int ii = wave;

    f32x4 zero = {0.f, 0.f, 0.f, 0.f};
    f32x4 acc[2][8];
    #pragma unroll
    for (int t = 0; t < 2; ++t)
        #pragma unroll
        for (int n = 0; n < 8; ++n) acc[t][n] = zero;

    // ---- layer 1: pair @ w01 (K=256) ----
    for (int c0 = 0; c0 < 256; c0 += 32) {
        __syncthreads();
        for (int e = tid; e < 512; e += 256) {
            int d = e >> 2, q = e & 3;
            *(uint4*)(BW + d * 40 + q * 8) =
                *(const uint4*)(w01t + (size_t)d * 256 + c0 + q * 8);
        }
        __syncthreads();
        half8 sib = *(const half8*)(SI + ii * 256 + c0 + quad * 8);
        half8 a0 = sib * *(const half8*)(SJ + l16 * 264 + c0 + quad * 8);
        half8 a1 = sib * *(const half8*)(SJ + (l16 + 16) * 264 + c0 + quad * 8);
        #pragma unroll
        for (int n = 0; n < 8; ++n) {
            half8 bf = *(const half8*)(BW + (n * 16 + l16) * 40 + quad * 8);
            acc[0][n] = __builtin_amdgcn_mfma_f32_16x16x32_f16(a0, bf, acc[0][n], 0, 0, 0);
            acc[1][n] = __builtin_amdgcn_mfma_f32_16x16x32_f16(a1, bf, acc[1][n], 0, 0, 0);
        }
    }
    // epilogue 1: bias+relu -> H1 fp16 (A-fragment-friendly layout)
    #pragma unroll
    for (int t = 0; t < 2; ++t)
        #pragma unroll
        for (int n = 0; n < 8; ++n) {
            int d = n * 16 + l16;
            float bias = b01[d];
            #pragma unroll
            for (int r = 0; r < 4; ++r) {
                int px = ii * 32 + t * 16 + quad * 4 + r;
                H1[px * 136 + d] = (f16)fmaxf(acc[t][n][r] + bias, 0.f);
            }
        }

    // ---- layer 2: H1 @ w02 (K=128) ----
    f32x4 acc2[2][4];
    #pragma unroll
    for (int t = 0; t < 2; ++t)
        #pragma unroll
        for (int n = 0; n < 4; ++n) acc2[t][n] = zero;

    for (int c0 = 0; c0 < 128; c0 += 32) {
        __syncthreads();   // first iter: H1 writes complete; later: BW reads done
        {
            int d = tid >> 2, q = tid & 3;
            if (d < 64)
                *(uint4*)(BW + d * 40 + q * 8) =
                    *(const uint4*)(w02t + (size_t)d * 128 + c0 + q * 8);
        }
        __syncthreads();
        half8 a0 = *(const half8*)(H1 + (ii * 32 + l16) * 136 + c0 + quad * 8);
        half8 a1 = *(const half8*)(H1 + (ii * 32 + 16 + l16) * 136 + c0 + quad * 8);
        #pragma unroll
        for (int n = 0; n < 4; ++n) {
            half8 bf = *(const half8*)(BW + (n * 16 + l16) * 40 + quad * 8);
            acc2[0][n] = __builtin_amdgcn_mfma_f32_16x16x32_f16(a0, bf, acc2[0][n], 0, 0, 0);
            acc2[1][n] = __builtin_amdgcn_mfma_f32_16x16x32_f16(a1, bf, acc2[1][n], 0, 0, 0);
        }
    }
    // epilogue 2: bias+relu -> H2 (aliases SJ/SI region; no overlap with H1/BW)
    #pragma unroll
    for (int t = 0; t < 2; ++t)
        #pragma unroll
        for (int n = 0; n < 4; ++n) {
            int e = n * 16 + l16;
            float bias = b02[e];
            #pragma unroll
            for (int r = 0; r < 4; ++r) {
                int px = ii * 32 + t * 16 + quad * 4 + r;
                H2[px * 72 + e] = (f16)fmaxf(acc2[t][n][r] + bias, 0.f);
            }
        }
    __syncthreads();
    // ---- layer 3: H2 @ w03 -> scalar ----
    if (tid < 128) {
        int px = tid;
        float s = b03[0];
        const f16* h = H2 + px * 72;
        #pragma unroll 8
        for (int c = 0; c < 64; ++c) s += (float)h[c] * W3s[c];
        int i = i0 + (px >> 5), j = j0 + (px & 31);
        if (j < N_TOK)
            X0[(size_t)b * NPX + i * N_TOK + j] = fmaxf(s, 0.f);
    }
}

// ---------------------------------------------------------------------------
// Symmetrize + softmax over 38416 logits, /2 folded in.
// ---------------------------------------------------------------------------
__global__ __launch_bounds__(1024) void symsoftmax(float* __restrict__ X0,
                                                   float* __restrict__ X1)
{
    __shared__ float red[32];
    __shared__ float red2[32];
    float* X = (blockIdx.y ? X1 : X0) + (long long)blockIdx.x * NPX;
    int tid = threadIdx.x;
    float v[38];
    float mx = -3.0e38f;
    #pragma unroll
    for (int p = 0; p < 38; ++p) {
        int e = tid + p * 1024;
        if (e < NPX) {
            int i = e / 196, j = e - i * 196;
            float t = X[e] + X[j * 196 + i];
            v[p] = t;
            mx = fmaxf(mx, t);
        } else v[p] = -3.0e38f;
    }
    #pragma unroll
    for (int off = 32; off > 0; off >>= 1) mx = fmaxf(mx, __shfl_xor(mx, off));
    if ((tid & 63) == 0) red[tid >> 6] = mx;
    __syncthreads();
    if (tid < 64) {
        float m = (tid < 16) ? red[tid] : -3.0e38f;
        #pragma unroll
        for (int off = 8; off > 0; off >>= 1) m = fmaxf(m, __shfl_xor(m, off));
        if (tid == 0) red[0] = m;
    }
    __syncthreads();
    mx = red[0];
    float s = 0.f;
    #pragma unroll
    for (int p = 0; p < 38; ++p) {
        int e = tid + p * 1024;
        float ex = (e < NPX) ? expf(v[p] - mx) : 0.f;
        v[p] = ex;
        s += ex;
    }
    #pragma unroll
    for (int off = 32; off > 0; off >>= 1) s += __shfl_xor(s, off);
    if ((tid & 63) == 0) red2[tid >> 6] = s;
    __syncthreads();
    if (tid < 64) {
        float m = (tid < 16) ? red2[tid] : 0.f;
        #pragma unroll
        for (int off = 8; off > 0; off >>= 1) m += __shfl_xor(m, off);
        if (tid == 0) red2[0] = m;
    }
    __syncthreads();
    float scale = 0.5f / red2[0];
    #pragma unroll
    for (int p = 0; p < 38; ++p) {
        int e = tid + p * 1024;
        if (e < NPX) X[e] = v[p] * scale;
    }
}

__global__ void combine_maps(float* __restrict__ X0, const float* __restrict__ X1, int n)
{
    int e = blockIdx.x * 256 + threadIdx.x;
    if (e < n) X0[e] += X1[e];
}

// ---------------------------------------------------------------------------
extern "C" void kernel_launch(void* const* d_in, const int* in_sizes, int n_in,
                              void* d_out, int out_size, void* d_ws, size_t ws_size,
                              hipStream_t stream)
{
    (void)in_sizes; (void)n_in; (void)out_size; (void)ws_size;
    const float* x     = (const float*)d_in[0];
    const float* w_prj = (const float*)d_in[1];
    const float* b_prj = (const float*)d_in[2];
    const float* w01   = (const float*)d_in[3];
    const float* b01   = (const float*)d_in[4];
    const float* w02   = (const float*)d_in[5];
    const float* b02   = (const float*)d_in[6];
    const float* w03   = (const float*)d_in[7];
    const float* b03   = (const float*)d_in[8];
    const float* w1    = (const float*)d_in[9];
    const float* b1    = (const float*)d_in[10];
    const float* w2    = (const float*)d_in[11];
    const float* b2    = (const float*)d_in[12];
    const float* w3    = (const float*)d_in[13];
    const float* b3    = (const float*)d_in[14];

    char* W = (char*)d_ws;
    float* sub  = (float*)(W + 0);          // 401408 f
    float* X0   = (float*)(W + 1605632);    // 307328 f
    float* X1   = (float*)(W + 2834944);    // 307328 f
    f16*   subh = (f16*)(W + 4064256);      // 401408 h
    f16*   w1t  = (f16*)(W + 4867072);      // 294912 h
    f16*   w2t  = (f16*)(W + 5456896);      // 73728 h
    f16*   w01t = (f16*)(W + 5604352);      // 32768 h
    f16*   w02t = (f16*)(W + 5669888);      // 8192 h
    f16*   Y1h  = (f16*)(W + 5686272);      // 8*38416*128 h = 78.7 MB
    f16*   Y2h  = (f16*)(W + 84358144);     // 8*38416*64 h  = 39.3 MB (end ~124 MB)

    // 1. sub = x @ w_prj + b_prj
    gemm_f32<<<dim3(4, 25, 1), 256, 0, stream>>>(
        x, w_prj, sub, 1568, 256, 2048, 2048, 256, 256, b_prj, 0, 0, 0);

    // 2. fp16 conversions
    cvt_f2h<<<dim3(1568), 256, 0, stream>>>(sub, subh, 401408);
    cvt_wt<<<dim3(1152), 256, 0, stream>>>(w1, w1t, 256, 128, 294912);
    cvt_wt<<<dim3(288),  256, 0, stream>>>(w2, w2t, 128, 64, 73728);
    cvt_wt<<<dim3(128),  256, 0, stream>>>(w01, w01t, 256, 128, 32768);
    cvt_wt<<<dim3(32),   256, 0, stream>>>(w02, w02t, 128, 64, 8192);

    // 3. branch 0 (MFMA) -> X0 logits
    branch0_mfma<<<dim3(7, 49, 8), 256, 0, stream>>>(
        subh, w01t, b01, w02t, b02, w03, b03, X0);

    // 4. conv branch (MFMA fp16) -> X1 logits
    conv1_mfma<<<dim3(7, 49, 8), 256, 0, stream>>>(subh, w1t, b1, Y1h);
    conv2_mfma<<<dim3(7, 98, 8), 256, 0, stream>>>(Y1h, w2t, b2, Y2h);
    conv3_h<<<dim3(151, 8), 256, 0, stream>>>(Y2h, w3, b3, X1);

    // 5. symmetrize + softmax both maps (x0.5 folded in)
    symsoftmax<<<dim3(8, 2), 1024, 0, stream>>>(X0, X1);

    // 6. M = map0 + map1
    combine_maps<<<dim3(1201), 256, 0, stream>>>(X0, X1, 307328);

    // 7. out[b] = M[b] @ x[b]
    gemm_f32<<<dim3(32, 4, 8), 256, 0, stream>>>(
        X0, x, (float*)d_out, 196, 2048, 196, 196, 2048, 2048, nullptr,
        38416, 401408, 401408);
}

// Round 4
// 655.259 us; speedup vs baseline: 7.1978x; 1.4278x over previous
//
#include <hip/hip_runtime.h>
#include <cmath>

#define N_TOK 196
#define NPX   38416
#define CDIM  256

typedef _Float16 f16;
typedef __attribute__((ext_vector_type(8))) _Float16 half8;
typedef __attribute__((ext_vector_type(4))) float f32x4;

// ---------------------------------------------------------------------------
// Projection GEMM, split-K: sub_partial[kz] = x[:, kz*256:+256] @ w_prj[kz...]
// M=1568, N=256, K=2048 split 8 ways. grid (4, 25, 8).
// ---------------------------------------------------------------------------
__global__ __launch_bounds__(256) void gemm_splitk(
    const float* __restrict__ A,   // x [1568][2048]
    const float* __restrict__ B,   // w_prj [2048][256]
    float* __restrict__ P)         // partials [8][1568][256]
{
    __shared__ float As[16][68];
    __shared__ float Bs[16][68];
    int tid = threadIdx.x;
    int tx = tid & 15, ty = tid >> 4;
    int m0 = blockIdx.y * 64, n0 = blockIdx.x * 64;
    int kz = blockIdx.z;
    float acc[4][4] = {};
    for (int k0 = kz * 256; k0 < kz * 256 + 256; k0 += 16) {
        __syncthreads();
        for (int e = tid; e < 1024; e += 256) {
            int m = e >> 4, kk = e & 15;
            int gm = m0 + m;
            As[kk][m] = (gm < 1568) ? A[(size_t)gm * 2048 + k0 + kk] : 0.f;
        }
        for (int e = tid; e < 1024; e += 256) {
            int kk = e >> 6, n = e & 63;
            Bs[kk][n] = B[(size_t)(k0 + kk) * 256 + n0 + n];
        }
        __syncthreads();
        #pragma unroll
        for (int kk = 0; kk < 16; ++kk) {
            float4 av = *(const float4*)&As[kk][ty * 4];
            float4 bv = *(const float4*)&Bs[kk][tx * 4];
            float a[4] = {av.x, av.y, av.z, av.w};
            float b[4] = {bv.x, bv.y, bv.z, bv.w};
            #pragma unroll
            for (int u = 0; u < 4; ++u)
                #pragma unroll
                for (int v = 0; v < 4; ++v) acc[u][v] += a[u] * b[v];
        }
    }
    float* Pz = P + (size_t)kz * 401408;
    #pragma unroll
    for (int u = 0; u < 4; ++u) {
        int gm = m0 + ty * 4 + u;
        if (gm >= 1568) continue;
        #pragma unroll
        for (int v = 0; v < 4; ++v) {
            int gn = n0 + tx * 4 + v;
            Pz[(size_t)gm * 256 + gn] = acc[u][v];
        }
    }
}

// sum 8 K-slices + bias -> fp16 sub
__global__ void reduce_subh(const float* __restrict__ P,
                            const float* __restrict__ bias,
                            f16* __restrict__ subh)
{
    int e = blockIdx.x * 256 + threadIdx.x;
    if (e >= 401408) return;
    float s = bias[e & 255];
    #pragma unroll
    for (int z = 0; z < 8; ++z) s += P[(size_t)z * 401408 + e];
    subh[e] = (f16)s;
}

// ---------------------------------------------------------------------------
// w [tap][Kc][D] fp32 -> wt [tap][D][Kc] fp16  (tap=1 gives plain transpose)
// ---------------------------------------------------------------------------
__global__ void cvt_wt(const float* __restrict__ w, f16* __restrict__ wt,
                       int Kc, int D, int total)
{
    int e = blockIdx.x * 256 + threadIdx.x;
    if (e >= total) return;
    int td = Kc * D;
    int tap = e / td, r = e - tap * td;
    int c = r / D, d = r - c * D;
    wt[(size_t)(tap * D + d) * Kc + c] = (f16)w[e];
}

// x [b][196][2048] fp32 -> xht [b][2048][200] fp16 (k-pad 200, zeros)
__global__ __launch_bounds__(256) void cvt_xT(const float* __restrict__ x,
                                              f16* __restrict__ xht)
{
    __shared__ float t[32][33];
    int b = blockIdx.z;
    int i0 = blockIdx.y * 32, n0 = blockIdx.x * 32;
    const float* xb = x + (size_t)b * 196 * 2048;
    for (int e = threadIdx.x; e < 1024; e += 256) {
        int r = e >> 5, c = e & 31;
        int gi = i0 + r;
        t[r][c] = (gi < 196) ? xb[(size_t)gi * 2048 + n0 + c] : 0.f;
    }
    __syncthreads();
    f16* xb2 = xht + (size_t)b * 2048 * 200;
    for (int e = threadIdx.x; e < 1024; e += 256) {
        int nl = e >> 5, il = e & 31;
        int gi = i0 + il, gn = n0 + nl;
        if (gi < 200) xb2[(size_t)gn * 200 + gi] = (f16)t[il][nl];
    }
}

// ---------------------------------------------------------------------------
// Conv1 MFMA implicit-GEMM, pair built on the fly (A = SI_bcast * SJ_frag).
// Tile: 128 px (4 i x 32 j) x 128 d; K = 9 taps x 256 c. Output fp16.
// ---------------------------------------------------------------------------
__global__ __launch_bounds__(256, 2) void conv1_mfma(
    const f16* __restrict__ sub_h,   // [8][196][256]
    const f16* __restrict__ w1t,     // [9][128][256]
    const float* __restrict__ b1,    // [128]
    f16* __restrict__ Y1h)           // [8][196][196][128]
{
    __shared__ f16 sh[17408];
    f16* SJ = sh;                    // [34][264]
    f16* SI = sh + 8976;             // [6][256]
    f16* BW = sh + 10512;            // [128][40]
    f16* OT = sh;                    // epilogue [128][136]

    int b = blockIdx.z;
    int i0 = blockIdx.y * 4, j0 = blockIdx.x * 32;
    int tid = threadIdx.x;
    const f16* subB = sub_h + (size_t)b * N_TOK * CDIM;

    uint4 zz = make_uint4(0, 0, 0, 0);
    for (int e = tid; e < 1088; e += 256) {
        int r = e >> 5, q = e & 31;
        int gj = j0 - 1 + r;
        uint4 v = zz;
        if (gj >= 0 && gj < N_TOK) v = *(const uint4*)(subB + gj * CDIM + q * 8);
        *(uint4*)(SJ + r * 264 + q * 8) = v;
    }
    if (tid < 192) {
        int r = tid >> 5, q = tid & 31;
        int gi = i0 - 1 + r;
        uint4 v = zz;
        if (gi >= 0 && gi < N_TOK) v = *(const uint4*)(subB + gi * CDIM + q * 8);
        *(uint4*)(SI + r * 256 + q * 8) = v;
    }

    int wave = tid >> 6, lane = tid & 63;
    int quad = lane >> 4, l16 = lane & 15;
    int ii = wave;

    f32x4 zero = {0.f, 0.f, 0.f, 0.f};
    f32x4 acc[2][8];
    #pragma unroll
    for (int t = 0; t < 2; ++t)
        #pragma unroll
        for (int n = 0; n < 8; ++n) acc[t][n] = zero;

    for (int tap = 0; tap < 9; ++tap) {
        int di = tap / 3 - 1, dj = tap % 3 - 1;
        for (int c0 = 0; c0 < 256; c0 += 32) {
            __syncthreads();
            for (int e = tid; e < 512; e += 256) {
                int d = e >> 2, q = e & 3;
                *(uint4*)(BW + d * 40 + q * 8) =
                    *(const uint4*)(w1t + (size_t)(tap * 128 + d) * 256 + c0 + q * 8);
            }
            __syncthreads();
            half8 sib = *(const half8*)(SI + (ii + di + 1) * 256 + c0 + quad * 8);
            half8 a0 = sib * *(const half8*)(SJ + (l16 + dj + 1) * 264 + c0 + quad * 8);
            half8 a1 = sib * *(const half8*)(SJ + (l16 + 16 + dj + 1) * 264 + c0 + quad * 8);
            half8 bf[8];
            #pragma unroll
            for (int n = 0; n < 8; ++n)
                bf[n] = *(const half8*)(BW + (n * 16 + l16) * 40 + quad * 8);
            #pragma unroll
            for (int n = 0; n < 8; ++n) {
                acc[0][n] = __builtin_amdgcn_mfma_f32_16x16x32_f16(a0, bf[n], acc[0][n], 0, 0, 0);
                acc[1][n] = __builtin_amdgcn_mfma_f32_16x16x32_f16(a1, bf[n], acc[1][n], 0, 0, 0);
            }
        }
    }
    __syncthreads();
    #pragma unroll
    for (int t = 0; t < 2; ++t)
        #pragma unroll
        for (int n = 0; n < 8; ++n) {
            int d = n * 16 + l16;
            float bias = b1[d];
            #pragma unroll
            for (int r = 0; r < 4; ++r) {
                int px = ii * 32 + t * 16 + quad * 4 + r;
                OT[px * 136 + d] = (f16)fmaxf(acc[t][n][r] + bias, 0.f);
            }
        }
    __syncthreads();
    f16* Yb = Y1h + (size_t)b * NPX * 128;
    for (int e = tid; e < 2048; e += 256) {
        int px = e >> 4, q = e & 15;
        int i = i0 + (px >> 5), j = j0 + (px & 31);
        if (j < N_TOK)
            *(uint4*)(Yb + ((size_t)i * N_TOK + j) * 128 + q * 8) =
                *(const uint4*)(OT + px * 136 + q * 8);
    }
}

// ---------------------------------------------------------------------------
// Conv2 MFMA: 3x3 dil (1,2), 128->64, fp16 in/out.
// ---------------------------------------------------------------------------
__global__ __launch_bounds__(256, 2) void conv2_mfma(
    const f16* __restrict__ Y1h, const f16* __restrict__ w2t,
    const float* __restrict__ b2, f16* __restrict__ Y2h)
{
    __shared__ f16 sh[22144];
    f16* Ys = sh;                    // [4][36][136]
    f16* BW = sh + 19584;            // [64][40]
    f16* OT = sh;                    // epilogue [64][72]

    int b = blockIdx.z;
    int i0 = blockIdx.y * 2, j0 = blockIdx.x * 32;
    int tid = threadIdx.x;
    const f16* Yb = Y1h + (size_t)b * NPX * 128;

    uint4 zz = make_uint4(0, 0, 0, 0);
    for (int e = tid; e < 2304; e += 256) {
        int ir = e / 576, rem = e - ir * 576;
        int jq = rem >> 4, q = rem & 15;
        int gi = i0 - 1 + ir, gj = j0 - 2 + jq;
        uint4 v = zz;
        if (gi >= 0 && gi < N_TOK && gj >= 0 && gj < N_TOK)
            v = *(const uint4*)(Yb + ((size_t)gi * N_TOK + gj) * 128 + q * 8);
        *(uint4*)(Ys + (ir * 36 + jq) * 136 + q * 8) = v;
    }

    int wave = tid >> 6, lane = tid & 63;
    int quad = lane >> 4, l16 = lane & 15;
    int ii = wave >> 1, jb = (wave & 1) * 16;

    f32x4 zero = {0.f, 0.f, 0.f, 0.f};
    f32x4 acc[4] = {zero, zero, zero, zero};

    for (int tap = 0; tap < 9; ++tap) {
        int di = tap / 3 - 1, dj2 = (tap % 3 - 1) * 2;
        for (int c0 = 0; c0 < 128; c0 += 32) {
            __syncthreads();
            {
                int d = tid >> 2, q = tid & 3;
                *(uint4*)(BW + d * 40 + q * 8) =
                    *(const uint4*)(w2t + (size_t)(tap * 64 + d) * 128 + c0 + q * 8);
            }
            __syncthreads();
            half8 a = *(const half8*)(Ys + ((ii + di + 1) * 36 + jb + l16 + dj2 + 2) * 136
                                      + c0 + quad * 8);
            #pragma unroll
            for (int n = 0; n < 4; ++n) {
                half8 bf = *(const half8*)(BW + (n * 16 + l16) * 40 + quad * 8);
                acc[n] = __builtin_amdgcn_mfma_f32_16x16x32_f16(a, bf, acc[n], 0, 0, 0);
            }
        }
    }
    __syncthreads();
    #pragma unroll
    for (int n = 0; n < 4; ++n) {
        int d = n * 16 + l16;
        float bias = b2[d];
        #pragma unroll
        for (int r = 0; r < 4; ++r) {
            int px = ii * 32 + jb + quad * 4 + r;
            OT[px * 72 + d] = (f16)fmaxf(acc[n][r] + bias, 0.f);
        }
    }
    __syncthreads();
    f16* Zb = Y2h + (size_t)b * NPX * 64;
    for (int e = tid; e < 512; e += 256) {
        int px = e >> 3, q = e & 7;
        int i = i0 + (px >> 5), j = j0 + (px & 31);
        if (j < N_TOK)
            *(uint4*)(Zb + ((size_t)i * N_TOK + j) * 64 + q * 8) =
                *(const uint4*)(OT + px * 72 + q * 8);
    }
}

// ---------------------------------------------------------------------------
// Conv3: 3x3 dil (1,4), 64->1, fp16 input, fp32 accumulate -> X1 logits.
// ---------------------------------------------------------------------------
__global__ __launch_bounds__(256) void conv3_h(
    const f16* __restrict__ Y2h, const float* __restrict__ w3,
    const float* __restrict__ b3, float* __restrict__ X1)
{
    __shared__ float w[576];
    int b = blockIdx.y;
    const f16* Yb = Y2h + (size_t)b * NPX * 64;
    for (int e = threadIdx.x; e < 576; e += 256) w[e] = w3[e];
    __syncthreads();
    int px = blockIdx.x * 256 + threadIdx.x;
    if (px >= NPX) return;
    int i = px / 196, j = px - i * 196;
    float s = b3[0];
    for (int tap = 0; tap < 9; ++tap) {
        int gi = i + tap / 3 - 1, gj = j + (tap % 3 - 1) * 4;
        if (gi < 0 || gi >= N_TOK || gj < 0 || gj >= N_TOK) continue;
        const half8* src = (const half8*)(Yb + ((size_t)gi * N_TOK + gj) * 64);
        const float* wt = w + tap * 64;
        #pragma unroll
        for (int q = 0; q < 8; ++q) {
            half8 h = src[q];
            #pragma unroll
            for (int e = 0; e < 8; ++e) s += (float)h[e] * wt[q * 8 + e];
        }
    }
    X1[(size_t)b * NPX + px] = fmaxf(s, 0.f);
}

// ---------------------------------------------------------------------------
// Branch 0 MFMA: pair -> 1x1 stack 256->128->64->1, all in one block.
// ---------------------------------------------------------------------------
__global__ __launch_bounds__(256, 2) void branch0_mfma(
    const f16* __restrict__ sub_h,
    const f16* __restrict__ w01t,    // [128][256]
    const float* __restrict__ b01,
    const f16* __restrict__ w02t,    // [64][128]
    const float* __restrict__ b02,
    const float* __restrict__ w03, const float* __restrict__ b03,
    float* __restrict__ X0)
{
    __shared__ f16 sh[32000];
    __shared__ float W3s[64];
    f16* SJ = sh;            // [32][264]
    f16* SI = sh + 8448;     // [4][256]
    f16* BW = sh + 9472;     // [128][40]
    f16* H1 = sh + 14592;    // [128][136]
    f16* H2 = sh;            // [128][72] (aliases SJ/SI)

    int b = blockIdx.z;
    int i0 = blockIdx.y * 4, j0 = blockIdx.x * 32;
    int tid = threadIdx.x;
    const f16* subB = sub_h + (size_t)b * N_TOK * CDIM;

    uint4 zz = make_uint4(0, 0, 0, 0);
    for (int e = tid; e < 1024; e += 256) {
        int r = e >> 5, q = e & 31;
        int gj = j0 + r;
        uint4 v = zz;
        if (gj < N_TOK) v = *(const uint4*)(subB + gj * CDIM + q * 8);
        *(uint4*)(SJ + r * 264 + q * 8) = v;
    }
    if (tid < 128) {
        int r = tid >> 5, q = tid & 31;
        int gi = i0 + r;
        uint4 v = zz;
        if (gi < N_TOK) v = *(const uint4*)(subB + gi * CDIM + q * 8);
        *(uint4*)(SI + r * 256 + q * 8) = v;
    }
    if (tid < 64) W3s[tid] = w03[tid];

    int wave = tid >> 6, lane = tid & 63;
    int quad = lane >> 4, l16 = lane & 15;
    int ii = wave;

    f32x4 zero = {0.f, 0.f, 0.f, 0.f};
    f32x4 acc[2][8];
    #pragma unroll
    for (int t = 0; t < 2; ++t)
        #pragma unroll
        for (int n = 0; n < 8; ++n) acc[t][n] = zero;

    for (int c0 = 0; c0 < 256; c0 += 32) {
        __syncthreads();
        for (int e = tid; e < 512; e += 256) {
            int d = e >> 2, q = e & 3;
            *(uint4*)(BW + d * 40 + q * 8) =
                *(const uint4*)(w01t + (size_t)d * 256 + c0 + q * 8);
        }
        __syncthreads();
        half8 sib = *(const half8*)(SI + ii * 256 + c0 + quad * 8);
        half8 a0 = sib * *(const half8*)(SJ + l16 * 264 + c0 + quad * 8);
        half8 a1 = sib * *(const half8*)(SJ + (l16 + 16) * 264 + c0 + quad * 8);
        #pragma unroll
        for (int n = 0; n < 8; ++n) {
            half8 bf = *(const half8*)(BW + (n * 16 + l16) * 40 + quad * 8);
            acc[0][n] = __builtin_amdgcn_mfma_f32_16x16x32_f16(a0, bf, acc[0][n], 0, 0, 0);
            acc[1][n] = __builtin_amdgcn_mfma_f32_16x16x32_f16(a1, bf, acc[1][n], 0, 0, 0);
        }
    }
    #pragma unroll
    for (int t = 0; t < 2; ++t)
        #pragma unroll
        for (int n = 0; n < 8; ++n) {
            int d = n * 16 + l16;
            float bias = b01[d];
            #pragma unroll
            for (int r = 0; r < 4; ++r) {
                int px = ii * 32 + t * 16 + quad * 4 + r;
                H1[px * 136 + d] = (f16)fmaxf(acc[t][n][r] + bias, 0.f);
            }
        }

    f32x4 acc2[2][4];
    #pragma unroll
    for (int t = 0; t < 2; ++t)
        #pragma unroll
        for (int n = 0; n < 4; ++n) acc2[t][n] = zero;

    for (int c0 = 0; c0 < 128; c0 += 32) {
        __syncthreads();
        {
            int d = tid >> 2, q = tid & 3;
            if (d < 64)
                *(uint4*)(BW + d * 40 + q * 8) =
                    *(const uint4*)(w02t + (size_t)d * 128 + c0 + q * 8);
        }
        __syncthreads();
        half8 a0 = *(const half8*)(H1 + (ii * 32 + l16) * 136 + c0 + quad * 8);
        half8 a1 = *(const half8*)(H1 + (ii * 32 + 16 + l16) * 136 + c0 + quad * 8);
        #pragma unroll
        for (int n = 0; n < 4; ++n) {
            half8 bf = *(const half8*)(BW + (n * 16 + l16) * 40 + quad * 8);
            acc2[0][n] = __builtin_amdgcn_mfma_f32_16x16x32_f16(a0, bf, acc2[0][n], 0, 0, 0);
            acc2[1][n] = __builtin_amdgcn_mfma_f32_16x16x32_f16(a1, bf, acc2[1][n], 0, 0, 0);
        }
    }
    #pragma unroll
    for (int t = 0; t < 2; ++t)
        #pragma unroll
        for (int n = 0; n < 4; ++n) {
            int e = n * 16 + l16;
            float bias = b02[e];
            #pragma unroll
            for (int r = 0; r < 4; ++r) {
                int px = ii * 32 + t * 16 + quad * 4 + r;
                H2[px * 72 + e] = (f16)fmaxf(acc2[t][n][r] + bias, 0.f);
            }
        }
    __syncthreads();
    if (tid < 128) {
        int px = tid;
        float s = b03[0];
        const f16* h = H2 + px * 72;
        #pragma unroll 8
        for (int c = 0; c < 64; ++c) s += (float)h[c] * W3s[c];
        int i = i0 + (px >> 5), j = j0 + (px & 31);
        if (j < N_TOK)
            X0[(size_t)b * NPX + i * N_TOK + j] = fmaxf(s, 0.f);
    }
}

// ---------------------------------------------------------------------------
// Symmetrize + softmax over 38416 logits, /2 folded in.
// ---------------------------------------------------------------------------
__global__ __launch_bounds__(1024) void symsoftmax(float* __restrict__ X0,
                                                   float* __restrict__ X1)
{
    __shared__ float red[32];
    __shared__ float red2[32];
    float* X = (blockIdx.y ? X1 : X0) + (long long)blockIdx.x * NPX;
    int tid = threadIdx.x;
    float v[38];
    float mx = -3.0e38f;
    #pragma unroll
    for (int p = 0; p < 38; ++p) {
        int e = tid + p * 1024;
        if (e < NPX) {
            int i = e / 196, j = e - i * 196;
            float t = X[e] + X[j * 196 + i];
            v[p] = t;
            mx = fmaxf(mx, t);
        } else v[p] = -3.0e38f;
    }
    #pragma unroll
    for (int off = 32; off > 0; off >>= 1) mx = fmaxf(mx, __shfl_xor(mx, off));
    if ((tid & 63) == 0) red[tid >> 6] = mx;
    __syncthreads();
    if (tid < 64) {
        float m = (tid < 16) ? red[tid] : -3.0e38f;
        #pragma unroll
        for (int off = 8; off > 0; off >>= 1) m = fmaxf(m, __shfl_xor(m, off));
        if (tid == 0) red[0] = m;
    }
    __syncthreads();
    mx = red[0];
    float s = 0.f;
    #pragma unroll
    for (int p = 0; p < 38; ++p) {
        int e = tid + p * 1024;
        float ex = (e < NPX) ? expf(v[p] - mx) : 0.f;
        v[p] = ex;
        s += ex;
    }
    #pragma unroll
    for (int off = 32; off > 0; off >>= 1) s += __shfl_xor(s, off);
    if ((tid & 63) == 0) red2[tid >> 6] = s;
    __syncthreads();
    if (tid < 64) {
        float m = (tid < 16) ? red2[tid] : 0.f;
        #pragma unroll
        for (int off = 8; off > 0; off >>= 1) m += __shfl_xor(m, off);
        if (tid == 0) red2[0] = m;
    }
    __syncthreads();
    float scale = 0.5f / red2[0];
    #pragma unroll
    for (int p = 0; p < 38; ++p) {
        int e = tid + p * 1024;
        if (e < NPX) X[e] = v[p] * scale;
    }
}

// Ph[b][i][200] = fp16( (X0+X1) * 512 ), row-padded with zeros
__global__ void combine_ph(const float* __restrict__ X0,
                           const float* __restrict__ X1,
                           f16* __restrict__ Ph)
{
    int e = blockIdx.x * 256 + threadIdx.x;
    if (e >= 8 * 196 * 200) return;
    int j = e % 200;
    int row = e / 200;              // b*196 + i
    f16 v = (f16)0.f;
    if (j < 196) {
        int src = row * 196 + j;
        v = (f16)((X0[src] + X1[src]) * 512.0f);
    }
    Ph[e] = v;
}

// ---------------------------------------------------------------------------
// out[b] = (Ph[b]/512) @ x[b] via fp16 MFMA. A=Ph [196][200], B=xht [2048][200].
// Tile 64 m x 128 n, K=256 (zero-padded past 196). grid (16, 4, 8).
// ---------------------------------------------------------------------------
__global__ __launch_bounds__(256, 2) void gemm_out(
    const f16* __restrict__ Ph, const f16* __restrict__ xht,
    float* __restrict__ out)
{
    __shared__ f16 As[64 * 72];
    __shared__ f16 Bs[128 * 72];
    int b = blockIdx.z;
    int n0 = blockIdx.x * 128, m0 = blockIdx.y * 64;
    int tid = threadIdx.x;
    const f16* Pb = Ph + (size_t)b * 196 * 200;
    const f16* xb = xht + (size_t)b * 2048 * 200;

    int wave = tid >> 6, lane = tid & 63;
    int quad = lane >> 4, l16 = lane & 15;

    f32x4 zero = {0.f, 0.f, 0.f, 0.f};
    f32x4 acc[8];
    #pragma unroll
    for (int n = 0; n < 8; ++n) acc[n] = zero;

    uint4 zz = make_uint4(0, 0, 0, 0);
    for (int k0 = 0; k0 < 256; k0 += 64) {
        __syncthreads();
        for (int e = tid; e < 512; e += 256) {
            int r = e >> 3, q = e & 7;
            int gm = m0 + r, k = k0 + q * 8;
            uint4 v = zz;
            if (gm < 196 && k < 200) v = *(const uint4*)(Pb + (size_t)gm * 200 + k);
            *(uint4*)(As + r * 72 + q * 8) = v;
        }
        for (int e = tid; e < 1024; e += 256) {
            int r = e >> 3, q = e & 7;
            int k = k0 + q * 8;
            uint4 v = zz;
            if (k < 200) v = *(const uint4*)(xb + (size_t)(n0 + r) * 200 + k);
            *(uint4*)(Bs + r * 72 + q * 8) = v;
        }
        __syncthreads();
        #pragma unroll
        for (int ks = 0; ks < 2; ++ks) {
            half8 a = *(const half8*)(As + (wave * 16 + l16) * 72 + ks * 32 + quad * 8);
            #pragma unroll
            for (int n = 0; n < 8; ++n) {
                half8 bf = *(const half8*)(Bs + (n * 16 + l16) * 72 + ks * 32 + quad * 8);
                acc[n] = __builtin_amdgcn_mfma_f32_16x16x32_f16(a, bf, acc[n], 0, 0, 0);
            }
        }
    }
    int m_base = m0 + wave * 16 + quad * 4;
    float* ob = out + (size_t)b * 196 * 2048;
    #pragma unroll
    for (int n = 0; n < 8; ++n) {
        int gn = n0 + n * 16 + l16;
        #pragma unroll
        for (int r = 0; r < 4; ++r) {
            int gm = m_base + r;
            if (gm < 196) ob[(size_t)gm * 2048 + gn] = acc[n][r] * (1.0f / 512.0f);
        }
    }
}

// ---------------------------------------------------------------------------
extern "C" void kernel_launch(void* const* d_in, const int* in_sizes, int n_in,
                              void* d_out, int out_size, void* d_ws, size_t ws_size,
                              hipStream_t stream)
{
    (void)in_sizes; (void)n_in; (void)out_size; (void)ws_size;
    const float* x     = (const float*)d_in[0];
    const float* w_prj = (const float*)d_in[1];
    const float* b_prj = (const float*)d_in[2];
    const float* w01   = (const float*)d_in[3];
    const float* b01   = (const float*)d_in[4];
    const float* w02   = (const float*)d_in[5];
    const float* b02   = (const float*)d_in[6];
    const float* w03   = (const float*)d_in[7];
    const float* b03   = (const float*)d_in[8];
    const float* w1    = (const float*)d_in[9];
    const float* b1    = (const float*)d_in[10];
    const float* w2    = (const float*)d_in[11];
    const float* b2    = (const float*)d_in[12];
    const float* w3    = (const float*)d_in[13];
    const float* b3    = (const float*)d_in[14];

    char* W = (char*)d_ws;
    float* part = (float*)(W + 0);          // 8*401408 f = 12.85 MB
    float* X0   = (float*)(W + 12845056);   // 307328 f
    float* X1   = (float*)(W + 14074368);   // 307328 f
    f16*   subh = (f16*)(W + 15303680);     // 401408 h
    f16*   w1t  = (f16*)(W + 16106496);     // 294912 h
    f16*   w2t  = (f16*)(W + 16696320);     // 73728 h
    f16*   w01t = (f16*)(W + 16843776);     // 32768 h
    f16*   w02t = (f16*)(W + 16909312);     // 8192 h
    f16*   Ph   = (f16*)(W + 16925696);     // 8*196*200 h
    f16*   xht  = (f16*)(W + 17552896);     // 8*2048*200 h
    f16*   Y1h  = (f16*)(W + 24106496);     // 8*38416*128 h = 78.7 MB
    f16*   Y2h  = (f16*)(W + 102782464);    // 8*38416*64 h  = 39.3 MB (end ~142 MB)

    // 1. projection: split-K gemm -> partials -> reduce -> subh (fp16)
    gemm_splitk<<<dim3(4, 25, 8), 256, 0, stream>>>(x, w_prj, part);
    reduce_subh<<<dim3(1568), 256, 0, stream>>>(part, b_prj, subh);

    // 2. weight conversions + x transpose
    cvt_wt<<<dim3(1152), 256, 0, stream>>>(w1, w1t, 256, 128, 294912);
    cvt_wt<<<dim3(288),  256, 0, stream>>>(w2, w2t, 128, 64, 73728);
    cvt_wt<<<dim3(128),  256, 0, stream>>>(w01, w01t, 256, 128, 32768);
    cvt_wt<<<dim3(32),   256, 0, stream>>>(w02, w02t, 128, 64, 8192);
    cvt_xT<<<dim3(64, 7, 8), 256, 0, stream>>>(x, xht);

    // 3. branch 0 (MFMA) -> X0 logits
    branch0_mfma<<<dim3(7, 49, 8), 256, 0, stream>>>(
        subh, w01t, b01, w02t, b02, w03, b03, X0);

    // 4. conv branch (MFMA fp16) -> X1 logits
    conv1_mfma<<<dim3(7, 49, 8), 256, 0, stream>>>(subh, w1t, b1, Y1h);
    conv2_mfma<<<dim3(7, 98, 8), 256, 0, stream>>>(Y1h, w2t, b2, Y2h);
    conv3_h<<<dim3(151, 8), 256, 0, stream>>>(Y2h, w3, b3, X1);

    // 5. symmetrize + softmax both maps (x0.5 folded in)
    symsoftmax<<<dim3(8, 2), 1024, 0, stream>>>(X0, X1);

    // 6. Ph = (map0 + map1) * 512 as fp16 (scale keeps probs out of subnormals)
    combine_ph<<<dim3(1225), 256, 0, stream>>>(X0, X1, Ph);

    // 7. out[b] = Ph[b]/512 @ x[b]  (fp16 MFMA, fp32 accum)
    gemm_out<<<dim3(16, 4, 8), 256, 0, stream>>>(Ph, xht, (float*)d_out);
}